// Round 10
// baseline (482.009 us; speedup 1.0000x reference)
//
#include <hip/hip_runtime.h>
#include <hip/hip_bf16.h>

#define V_N 30000
#define E_N 500000

__device__ __forceinline__ float lrelu(float x) { return fmaxf(x, 0.2f * x); }
__device__ __forceinline__ unsigned short f2bf(float f) {
    __hip_bfloat16 h = __float2bfloat16(f);
    return *reinterpret_cast<unsigned short*>(&h);
}
__device__ __forceinline__ float bf_lo(unsigned u) { return __uint_as_float(u << 16); }
__device__ __forceinline__ float bf_hi(unsigned u) { return __uint_as_float(u & 0xffff0000u); }

// t + dpp(t); rows excluded by RMASK receive +0 (old=0).
template<int CTRL, int RMASK>
__device__ __forceinline__ float dpp_add(float t) {
    int b = __builtin_amdgcn_update_dpp(0, __float_as_int(t), CTRL, RMASK, 0xF, true);
    return t + __int_as_float(b);
}

// Sum over each independent 32-lane group, valid on all 32 lanes.
// ror1/2/4/8 -> every lane holds its 16-row sum; bcast15 (rows 1,3) -> rows
// 1,3 hold their group's full 32-sum; shfl_xor(16)+select completes rows 0,2.
// NO cross-group (bcast31) step: the two 32-groups stay independent.
__device__ __forceinline__ float group_sum(float t, int lane) {
    t = dpp_add<0x121, 0xF>(t);   // row_ror:1
    t = dpp_add<0x122, 0xF>(t);   // row_ror:2
    t = dpp_add<0x124, 0xF>(t);   // row_ror:4
    t = dpp_add<0x128, 0xF>(t);   // row_ror:8
    t = dpp_add<0x142, 0xA>(t);   // row_bcast15 into rows 1,3
    float u = __shfl_xor(t, 16);
    return (lane & 16) ? t : u;
}

// ---------------------------------------------------------------------------
// Kernel A (fused): blocks [0, 3750): src-side node transforms (Was, Wms),
// bf16-packed; blocks [3750, 5704): dst-degree histogram.
// tab layout per node: 32 x uint4; lane's uint4 = {att01, att23, msg01, msg23}.
// ---------------------------------------------------------------------------
__global__ __launch_bounds__(256) void xform_hist(
    const float* __restrict__ nf,
    const float* __restrict__ Was, const float* __restrict__ bas,
    const float* __restrict__ Wms, const float* __restrict__ bms,
    const int* __restrict__ dst,
    uint4* __restrict__ tab_s, int* __restrict__ deg)
{
    int tid = threadIdx.x;
    if (blockIdx.x >= 3750) {                      // histogram part
        int i = (blockIdx.x - 3750) * 256 + tid;
        if (i < E_N) atomicAdd(&deg[dst[i]], 1);
        return;
    }
    __shared__ float w0[1024], w2[1024];
    for (int i = tid; i < 1024; i += 256) { w0[i] = Was[i]; w2[i] = Wms[i]; }
    __syncthreads();
    int lane = tid & 31;
    int n = blockIdx.x * 8 + (tid >> 5);           // 3750*8 = 30000 exact
    float att[4], msg[4];
    #pragma unroll
    for (int h = 0; h < 4; ++h) {
        float x = nf[(size_t)n * 128 + h * 32 + lane];
        float a0 = bas[lane], a2 = bms[lane];
        #pragma unroll
        for (int k = 0; k < 32; ++k) {
            float xk = __shfl(x, k, 32);
            a0 = fmaf(xk, w0[k * 32 + lane], a0);
            a2 = fmaf(xk, w2[k * 32 + lane], a2);
        }
        att[h] = a0; msg[h] = a2;
    }
    uint4 u;
    u.x = f2bf(att[0]) | ((unsigned)f2bf(att[1]) << 16);
    u.y = f2bf(att[2]) | ((unsigned)f2bf(att[3]) << 16);
    u.z = f2bf(msg[0]) | ((unsigned)f2bf(msg[1]) << 16);
    u.w = f2bf(msg[2]) | ((unsigned)f2bf(msg[3]) << 16);
    tab_s[(size_t)n * 32 + lane] = u;
}

// ---------------------------------------------------------------------------
// Exclusive scan of deg -> rowptr, cursor (single block, wave64 scans).
// ---------------------------------------------------------------------------
__global__ __launch_bounds__(1024) void scan_k(
    const int* __restrict__ deg, int* __restrict__ rowptr, int* __restrict__ cursor)
{
    __shared__ int wsum[16];
    __shared__ int carry_s;
    int tid = threadIdx.x;
    int lane = tid & 63, wv = tid >> 6;
    if (tid == 0) carry_s = 0;
    __syncthreads();
    for (int base = 0; base < V_N; base += 1024) {
        int i = base + tid;
        int v = (i < V_N) ? deg[i] : 0;
        int x = v;
        #pragma unroll
        for (int off = 1; off < 64; off <<= 1) {
            int t = __shfl_up(x, off, 64);
            if (lane >= off) x += t;
        }
        if (lane == 63) wsum[wv] = x;
        __syncthreads();
        if (wv == 0 && lane < 16) {
            int s = wsum[lane];
            #pragma unroll
            for (int off = 1; off < 16; off <<= 1) {
                int t = __shfl_up(s, off, 64);
                if (lane >= off) s += t;
            }
            wsum[lane] = s;
        }
        __syncthreads();
        int woff  = (wv == 0) ? 0 : wsum[wv - 1];
        int carry = carry_s;
        int excl  = carry + woff + x - v;
        if (i < V_N) { rowptr[i] = excl; cursor[i] = excl; }
        __syncthreads();
        if (tid == 1023) carry_s = carry + wsum[15];
        __syncthreads();
    }
    if (tid == 0) rowptr[V_N] = carry_s;
}

// ---------------------------------------------------------------------------
// Kernel B (fused scatter + streaming edge GEMV). Group per edge:
// lane 0 claims CSR slot p and writes csr_src; group computes ea/me
// (shfl+LDS GEMV, coalesced ef) and writes em[p] bf16-packed.
// Slot order within a node is atomic-order-dependent -> only permutes the
// f32 summation order downstream (accepted; threshold headroom 11x).
// ---------------------------------------------------------------------------
__global__ __launch_bounds__(256) void scatter_gemv(
    const float* __restrict__ ef, const int* __restrict__ src, const int* __restrict__ dst,
    int* __restrict__ cursor,
    const float* __restrict__ Wae, const float* __restrict__ bae,
    const float* __restrict__ Wme, const float* __restrict__ bme,
    int* __restrict__ csr_src, unsigned* __restrict__ em)
{
    __shared__ float wa[1024], wm[1024];
    int tid = threadIdx.x;
    for (int i = tid; i < 1024; i += 256) { wa[i] = Wae[i]; wm[i] = Wme[i]; }
    __syncthreads();
    int lane = tid & 31;
    int gid = (blockIdx.x * 256 + tid) >> 5;
    int ngr = (gridDim.x * 256) >> 5;
    float ba = bae[lane], bm = bme[lane];
    for (int e = gid; e < E_N; e += ngr) {
        float x = ef[(size_t)e * 32 + lane];
        int p0 = 0;
        if (lane == 0) {
            p0 = atomicAdd(&cursor[dst[e]], 1);
            csr_src[p0] = src[e];
        }
        int p = __shfl(p0, 0, 32);
        float ea = ba, me = bm;
        #pragma unroll
        for (int k = 0; k < 32; ++k) {
            float xk = __shfl(x, k, 32);
            ea = fmaf(xk, wa[k * 32 + lane], ea);
            me = fmaf(xk, wm[k * 32 + lane], me);
        }
        em[(size_t)p * 32 + lane] = f2bf(ea) | ((unsigned)f2bf(me) << 16);
    }
}

// ---------------------------------------------------------------------------
// Kernel C: per-dst aggregation. Work-queue (1 node/pop per 32-group),
// depth-2 prefetch of {csr_src, tab_s, em}, DPP group_sum score reduce.
// Prologue per node: dst transforms (Wad,Wmd) + Wwn GEMV in registers.
// ---------------------------------------------------------------------------
__global__ __launch_bounds__(256) void node_gather2(
    const int* __restrict__ rowptr, const int* __restrict__ csr_src,
    const unsigned* __restrict__ em, const uint4* __restrict__ tab_s,
    const float* __restrict__ Wad, const float* __restrict__ bad,
    const float* __restrict__ Wmd, const float* __restrict__ bmd,
    const float* __restrict__ Wdot, const float* __restrict__ bdot,
    const float* __restrict__ Wwn, const float* __restrict__ bwn,
    const float* __restrict__ nf,
    int* __restrict__ qctr,
    float* __restrict__ out)
{
    __shared__ float w1[1024], w3[1024], ww[1024], wd[32];
    int tid = threadIdx.x;
    for (int i = tid; i < 1024; i += 256) { w1[i] = Wad[i]; w3[i] = Wmd[i]; ww[i] = Wwn[i]; }
    if (tid < 32) wd[tid] = Wdot[tid];
    __syncthreads();
    int lane = tid & 31;
    float wdl = wd[lane], bd = bdot[0];

    for (;;) {
        int n0 = 0;
        if (lane == 0) n0 = atomicAdd(qctr, 1);
        int n = __shfl(n0, 0, 32);
        if (n >= V_N) break;

        // prologue: dst transforms + Wwn path
        float da[4], dm[4], wn[4];
        #pragma unroll
        for (int h = 0; h < 4; ++h) {
            float x = nf[(size_t)n * 128 + h * 32 + lane];
            float a1 = bad[lane], a3 = bmd[lane], aw = bwn[lane];
            #pragma unroll
            for (int k = 0; k < 32; ++k) {
                float xk = __shfl(x, k, 32);
                a1 = fmaf(xk, w1[k * 32 + lane], a1);
                a3 = fmaf(xk, w3[k * 32 + lane], a3);
                aw = fmaf(xk, ww[k * 32 + lane], aw);
            }
            da[h] = a1; dm[h] = a3; wn[h] = aw;
        }

        float acc0 = 0.f, acc1 = 0.f, acc2 = 0.f, acc3 = 0.f;
        float s0 = 0.f, s1 = 0.f, s2 = 0.f, s3 = 0.f;
        int p0 = rowptr[n], p1 = rowptr[n + 1];

        uint4 gA = make_uint4(0,0,0,0), gB = gA;
        unsigned eA = 0, eB = 0;
        if (p0 < p1) {
            int sA = csr_src[p0];
            gA = tab_s[(size_t)sA * 32 + lane];
            eA = em[(size_t)p0 * 32 + lane];
        }
        if (p0 + 1 < p1) {
            int sB = csr_src[p0 + 1];
            gB = tab_s[(size_t)sB * 32 + lane];
            eB = em[(size_t)(p0 + 1) * 32 + lane];
        }
        for (int p = p0; p < p1; ++p) {
            uint4 g = gA; unsigned ev = eA;
            gA = gB; eA = eB;
            if (p + 2 < p1) {                      // depth-2 prefetch
                int sn = csr_src[p + 2];
                gB = tab_s[(size_t)sn * 32 + lane];
                eB = em[(size_t)(p + 2) * 32 + lane];
            }
            float ea = bf_lo(ev), me = bf_hi(ev);
            float t0 = lrelu(bf_lo(g.x) + da[0] + ea) * wdl;
            float t1 = lrelu(bf_hi(g.x) + da[1] + ea) * wdl;
            float t2 = lrelu(bf_lo(g.y) + da[2] + ea) * wdl;
            float t3 = lrelu(bf_hi(g.y) + da[3] + ea) * wdl;
            t0 = group_sum(t0, lane);
            t1 = group_sum(t1, lane);
            t2 = group_sum(t2, lane);
            t3 = group_sum(t3, lane);
            float x0 = __expf(t0 + bd), x1 = __expf(t1 + bd);
            float x2 = __expf(t2 + bd), x3 = __expf(t3 + bd);
            float m0 = lrelu(bf_lo(g.z) + dm[0] + me);
            float m1 = lrelu(bf_hi(g.z) + dm[1] + me);
            float m2 = lrelu(bf_lo(g.w) + dm[2] + me);
            float m3 = lrelu(bf_hi(g.w) + dm[3] + me);
            acc0 = fmaf(x0, m0, acc0); s0 += x0;
            acc1 = fmaf(x1, m1, acc1); s1 += x1;
            acc2 = fmaf(x2, m2, acc2); s2 += x2;
            acc3 = fmaf(x3, m3, acc3); s3 += x3;
        }
        #pragma unroll
        for (int h = 0; h < 4; ++h) {
            float accv = (h == 0) ? acc0 : (h == 1) ? acc1 : (h == 2) ? acc2 : acc3;
            float sv   = (h == 0) ? s0   : (h == 1) ? s1   : (h == 2) ? s2   : s3;
            float f = (sv > 0.f) ? accv / sv : 0.f;
            out[(size_t)n * 128 + h * 32 + lane] = lrelu(f + wn[h]);
        }
    }
}

extern "C" void kernel_launch(void* const* d_in, const int* in_sizes, int n_in,
                              void* d_out, int out_size, void* d_ws, size_t ws_size,
                              hipStream_t stream)
{
    const float* nf  = (const float*)d_in[0];
    const float* ef  = (const float*)d_in[1];
    const int*   src = (const int*)d_in[2];
    const int*   dst = (const int*)d_in[3];
    const float* Was = (const float*)d_in[4],  *bas = (const float*)d_in[5];
    const float* Wad = (const float*)d_in[6],  *bad = (const float*)d_in[7];
    const float* Wae = (const float*)d_in[8],  *bae = (const float*)d_in[9];
    const float* Wdot= (const float*)d_in[10], *bdot= (const float*)d_in[11];
    const float* Wms = (const float*)d_in[12], *bms = (const float*)d_in[13];
    const float* Wmd = (const float*)d_in[14], *bmd = (const float*)d_in[15];
    const float* Wme = (const float*)d_in[16], *bme = (const float*)d_in[17];
    const float* Wwn = (const float*)d_in[18], *bwn = (const float*)d_in[19];

    // ws layout (~81.7 MB):
    unsigned* em    = (unsigned*)d_ws;                         // E*32 u32 = 64 MB
    uint4*    tab_s = (uint4*)(em + (size_t)E_N * 32);         // V*32 uint4 = 15.36 MB
    int*      qctr  = (int*)((char*)tab_s + (size_t)V_N * 512);// 1
    int*      deg   = qctr + 1;                                // V
    int*      rowptr= deg + V_N;                               // V+1
    int*      cursor= rowptr + V_N + 1;                        // V
    int*      csr_src = cursor + V_N;                          // E

    // zero qctr + deg in one shot (adjacent)
    hipMemsetAsync(qctr, 0, (V_N + 1) * sizeof(int), stream);

    xform_hist<<<3750 + 1954, 256, 0, stream>>>(nf, Was, bas, Wms, bms, dst,
                                                tab_s, deg);
    scan_k<<<1, 1024, 0, stream>>>(deg, rowptr, cursor);
    scatter_gemv<<<4096, 256, 0, stream>>>(ef, src, dst, cursor,
                                           Wae, bae, Wme, bme, csr_src, em);
    node_gather2<<<1024, 256, 0, stream>>>(rowptr, csr_src, em, tab_s,
                                           Wad, bad, Wmd, bmd, Wdot, bdot, Wwn, bwn,
                                           nf, qctr, (float*)d_out);
}

// Round 11
// 470.886 us; speedup vs baseline: 1.0236x; 1.0236x over previous
//
#include <hip/hip_runtime.h>
#include <hip/hip_bf16.h>

#define V_N 30000
#define E_N 500000

__device__ __forceinline__ float lrelu(float x) { return fmaxf(x, 0.2f * x); }
__device__ __forceinline__ unsigned short f2bf(float f) {
    __hip_bfloat16 h = __float2bfloat16(f);
    return *reinterpret_cast<unsigned short*>(&h);
}
__device__ __forceinline__ float bf_lo(unsigned u) { return __uint_as_float(u << 16); }
__device__ __forceinline__ float bf_hi(unsigned u) { return __uint_as_float(u & 0xffff0000u); }

// ---------------------------------------------------------------------------
// Kernel A: src-side node transforms (Was, Wms), bf16-packed for 1-load gather.
// Layout per node: 32 lanes x uint4; lane's uint4 = {att0|att1, att2|att3,
// msg0|msg1, msg2|msg3} (bf16 pairs), feature = lane.   (R9-proven)
// ---------------------------------------------------------------------------
__global__ __launch_bounds__(256) void node_xform_s(
    const float* __restrict__ nf,
    const float* __restrict__ Was, const float* __restrict__ bas,
    const float* __restrict__ Wms, const float* __restrict__ bms,
    uint4* __restrict__ tab_s)
{
    __shared__ float w0[1024], w2[1024];
    int tid = threadIdx.x;
    for (int i = tid; i < 1024; i += 256) { w0[i] = Was[i]; w2[i] = Wms[i]; }
    __syncthreads();
    int lane = tid & 31;
    int n = blockIdx.x * 8 + (tid >> 5);          // 3750*8 = 30000 exact
    float att[4], msg[4];
    #pragma unroll
    for (int h = 0; h < 4; ++h) {
        float x = nf[(size_t)n * 128 + h * 32 + lane];
        float a0 = bas[lane], a2 = bms[lane];
        #pragma unroll
        for (int k = 0; k < 32; ++k) {
            float xk = __shfl(x, k, 32);
            a0 = fmaf(xk, w0[k * 32 + lane], a0);
            a2 = fmaf(xk, w2[k * 32 + lane], a2);
        }
        att[h] = a0; msg[h] = a2;
    }
    uint4 u;
    u.x = f2bf(att[0]) | ((unsigned)f2bf(att[1]) << 16);
    u.y = f2bf(att[2]) | ((unsigned)f2bf(att[3]) << 16);
    u.z = f2bf(msg[0]) | ((unsigned)f2bf(msg[1]) << 16);
    u.w = f2bf(msg[2]) | ((unsigned)f2bf(msg[3]) << 16);
    tab_s[(size_t)n * 32 + lane] = u;
}

// ---------------------------------------------------------------------------
// CSR build: histogram -> exclusive scan -> scatter (records pos[e], csr_src).
// (R9-proven, unchanged)
// ---------------------------------------------------------------------------
__global__ __launch_bounds__(256) void hist_k(
    const int* __restrict__ dst, int* __restrict__ deg)
{
    int i = blockIdx.x * 256 + threadIdx.x;
    if (i < E_N) atomicAdd(&deg[dst[i]], 1);
}

__global__ __launch_bounds__(1024) void scan_k(
    const int* __restrict__ deg, int* __restrict__ rowptr, int* __restrict__ cursor)
{
    __shared__ int wsum[16];
    __shared__ int carry_s;
    int tid = threadIdx.x;
    int lane = tid & 63, wv = tid >> 6;
    if (tid == 0) carry_s = 0;
    __syncthreads();
    for (int base = 0; base < V_N; base += 1024) {
        int i = base + tid;
        int v = (i < V_N) ? deg[i] : 0;
        int x = v;
        #pragma unroll
        for (int off = 1; off < 64; off <<= 1) {
            int t = __shfl_up(x, off, 64);
            if (lane >= off) x += t;
        }
        if (lane == 63) wsum[wv] = x;
        __syncthreads();
        if (wv == 0 && lane < 16) {
            int s = wsum[lane];
            #pragma unroll
            for (int off = 1; off < 16; off <<= 1) {
                int t = __shfl_up(s, off, 64);
                if (lane >= off) s += t;
            }
            wsum[lane] = s;
        }
        __syncthreads();
        int woff  = (wv == 0) ? 0 : wsum[wv - 1];
        int carry = carry_s;
        int excl  = carry + woff + x - v;
        if (i < V_N) { rowptr[i] = excl; cursor[i] = excl; }
        __syncthreads();
        if (tid == 1023) carry_s = carry + wsum[15];
        __syncthreads();
    }
    if (tid == 0) rowptr[V_N] = carry_s;
}

__global__ __launch_bounds__(256) void scatter_k(
    const int* __restrict__ dst, const int* __restrict__ src,
    int* __restrict__ cursor, int* __restrict__ pos, int* __restrict__ csr_src)
{
    int i = blockIdx.x * 256 + threadIdx.x;
    if (i < E_N) {
        int p = atomicAdd(&cursor[dst[i]], 1);
        pos[i] = p;
        csr_src[p] = src[i];
    }
}

// ---------------------------------------------------------------------------
// Kernel B: STREAMING edge GEMV (coalesced ef, no gathers). (R9-proven)
// ---------------------------------------------------------------------------
__global__ __launch_bounds__(256) void edge_gemv(
    const float* __restrict__ ef, const int* __restrict__ pos,
    const float* __restrict__ Wae, const float* __restrict__ bae,
    const float* __restrict__ Wme, const float* __restrict__ bme,
    unsigned* __restrict__ em)
{
    __shared__ float wa[1024], wm[1024];
    int tid = threadIdx.x;
    for (int i = tid; i < 1024; i += 256) { wa[i] = Wae[i]; wm[i] = Wme[i]; }
    __syncthreads();
    int lane = tid & 31;
    int gid = (blockIdx.x * 256 + tid) >> 5;
    int ngr = (gridDim.x * 256) >> 5;
    float ba = bae[lane], bm = bme[lane];
    for (int e = gid; e < E_N; e += ngr) {
        float x = ef[(size_t)e * 32 + lane];
        int p = pos[e];
        float ea = ba, me = bm;
        #pragma unroll
        for (int k = 0; k < 32; ++k) {
            float xk = __shfl(x, k, 32);
            ea = fmaf(xk, wa[k * 32 + lane], ea);
            me = fmaf(xk, wm[k * 32 + lane], me);
        }
        em[(size_t)p * 32 + lane] = f2bf(ea) | ((unsigned)f2bf(me) << 16);
    }
}

// ---------------------------------------------------------------------------
// Kernel C: per-dst aggregation (R9 structure: static 8 nodes/block, butterfly
// reduce, per-node dst/Wwn prologue). SINGLE CHANGE vs R9:
//   cooperative chunked csr_src load (1 coalesced load / 32 edges; per-edge
//   index via v_readlane) + depth-2 prefetch of {tab_s, em}. This breaks the
//   csr_src -> tab_s chained latency. __launch_bounds__(256,4) pins VGPR<=128.
// ---------------------------------------------------------------------------
__global__ __launch_bounds__(256, 4) void node_gather2(
    const int* __restrict__ rowptr, const int* __restrict__ csr_src,
    const unsigned* __restrict__ em, const uint4* __restrict__ tab_s,
    const float* __restrict__ Wad, const float* __restrict__ bad,
    const float* __restrict__ Wmd, const float* __restrict__ bmd,
    const float* __restrict__ Wdot, const float* __restrict__ bdot,
    const float* __restrict__ Wwn, const float* __restrict__ bwn,
    const float* __restrict__ nf,
    float* __restrict__ out)
{
    __shared__ float w1[1024], w3[1024], ww[1024], wd[32];
    int tid = threadIdx.x;
    for (int i = tid; i < 1024; i += 256) { w1[i] = Wad[i]; w3[i] = Wmd[i]; ww[i] = Wwn[i]; }
    if (tid < 32) wd[tid] = Wdot[tid];
    __syncthreads();
    int lane = tid & 31;
    int n = blockIdx.x * 8 + (tid >> 5);          // 3750*8 = 30000 exact
    float wdl = wd[lane], bd = bdot[0];

    // per-node prologue: da/dm (dst transforms) + wn (Wwn path), all heads
    float da[4], dm[4], wn[4];
    #pragma unroll
    for (int h = 0; h < 4; ++h) {
        float x = nf[(size_t)n * 128 + h * 32 + lane];
        float a1 = bad[lane], a3 = bmd[lane], aw = bwn[lane];
        #pragma unroll
        for (int k = 0; k < 32; ++k) {
            float xk = __shfl(x, k, 32);
            a1 = fmaf(xk, w1[k * 32 + lane], a1);
            a3 = fmaf(xk, w3[k * 32 + lane], a3);
            aw = fmaf(xk, ww[k * 32 + lane], aw);
        }
        da[h] = a1; dm[h] = a3; wn[h] = aw;
    }

    float acc0 = 0.f, acc1 = 0.f, acc2 = 0.f, acc3 = 0.f;
    float s0 = 0.f, s1 = 0.f, s2 = 0.f, s3 = 0.f;
    int p0 = rowptr[n], p1 = rowptr[n + 1];

    for (int base = p0; base < p1; base += 32) {
        int cnt = (p1 - base < 32) ? (p1 - base) : 32;
        int q = base + lane;
        int sidx = (q < p1) ? csr_src[q] : 0;     // 1 coalesced load / 32 edges
        uint4 gA, gB = make_uint4(0, 0, 0, 0);
        unsigned eA, eB = 0;
        {
            int s0i = __shfl(sidx, 0, 32);
            gA = tab_s[(size_t)s0i * 32 + lane];
            eA = em[(size_t)base * 32 + lane];
        }
        if (cnt > 1) {
            int s1i = __shfl(sidx, 1, 32);
            gB = tab_s[(size_t)s1i * 32 + lane];
            eB = em[(size_t)(base + 1) * 32 + lane];
        }
        for (int j = 0; j < cnt; ++j) {
            uint4 g = gA; unsigned ev = eA;
            gA = gB; eA = eB;
            if (j + 2 < cnt) {                     // depth-2 prefetch
                int sn = __shfl(sidx, j + 2, 32);  // v_readlane (uniform idx)
                gB = tab_s[(size_t)sn * 32 + lane];
                eB = em[(size_t)(base + j + 2) * 32 + lane];
            }
            float ea = bf_lo(ev), me = bf_hi(ev);
            float t0 = lrelu(bf_lo(g.x) + da[0] + ea) * wdl;
            float t1 = lrelu(bf_hi(g.x) + da[1] + ea) * wdl;
            float t2 = lrelu(bf_lo(g.y) + da[2] + ea) * wdl;
            float t3 = lrelu(bf_hi(g.y) + da[3] + ea) * wdl;
            #pragma unroll
            for (int off = 16; off; off >>= 1) {
                t0 += __shfl_xor(t0, off, 32);
                t1 += __shfl_xor(t1, off, 32);
                t2 += __shfl_xor(t2, off, 32);
                t3 += __shfl_xor(t3, off, 32);
            }
            float x0 = __expf(t0 + bd), x1 = __expf(t1 + bd);
            float x2 = __expf(t2 + bd), x3 = __expf(t3 + bd);
            float m0 = lrelu(bf_lo(g.z) + dm[0] + me);
            float m1 = lrelu(bf_hi(g.z) + dm[1] + me);
            float m2 = lrelu(bf_lo(g.w) + dm[2] + me);
            float m3 = lrelu(bf_hi(g.w) + dm[3] + me);
            acc0 = fmaf(x0, m0, acc0); s0 += x0;
            acc1 = fmaf(x1, m1, acc1); s1 += x1;
            acc2 = fmaf(x2, m2, acc2); s2 += x2;
            acc3 = fmaf(x3, m3, acc3); s3 += x3;
        }
    }
    // epilogue: out = lrelu(feat/ssum + wn)
    #pragma unroll
    for (int h = 0; h < 4; ++h) {
        float accv = (h == 0) ? acc0 : (h == 1) ? acc1 : (h == 2) ? acc2 : acc3;
        float sv   = (h == 0) ? s0   : (h == 1) ? s1   : (h == 2) ? s2   : s3;
        float f = (sv > 0.f) ? accv / sv : 0.f;
        out[(size_t)n * 128 + h * 32 + lane] = lrelu(f + wn[h]);
    }
}

extern "C" void kernel_launch(void* const* d_in, const int* in_sizes, int n_in,
                              void* d_out, int out_size, void* d_ws, size_t ws_size,
                              hipStream_t stream)
{
    const float* nf  = (const float*)d_in[0];
    const float* ef  = (const float*)d_in[1];
    const int*   src = (const int*)d_in[2];
    const int*   dst = (const int*)d_in[3];
    const float* Was = (const float*)d_in[4],  *bas = (const float*)d_in[5];
    const float* Wad = (const float*)d_in[6],  *bad = (const float*)d_in[7];
    const float* Wae = (const float*)d_in[8],  *bae = (const float*)d_in[9];
    const float* Wdot= (const float*)d_in[10], *bdot= (const float*)d_in[11];
    const float* Wms = (const float*)d_in[12], *bms = (const float*)d_in[13];
    const float* Wmd = (const float*)d_in[14], *bmd = (const float*)d_in[15];
    const float* Wme = (const float*)d_in[16], *bme = (const float*)d_in[17];
    const float* Wwn = (const float*)d_in[18], *bwn = (const float*)d_in[19];

    // ws layout (83.7 MB total):
    unsigned* em   = (unsigned*)d_ws;                       // E*32 u32 = 64 MB
    uint4*  tab_s  = (uint4*)(em + (size_t)E_N * 32);       // V*32 uint4 = 15.36 MB
    int*    deg    = (int*)((char*)tab_s + (size_t)V_N * 512); // V
    int*    rowptr = deg + V_N;                             // V+1
    int*    cursor = rowptr + V_N + 1;                      // V
    int*    pos    = cursor + V_N;                          // E
    int*    csr_src= pos + E_N;                             // E

    hipMemsetAsync(deg, 0, V_N * sizeof(int), stream);

    const int ebk = (E_N + 255) / 256;                      // 1954 blocks
    const int nb  = V_N / 8;                                // 3750 blocks

    node_xform_s<<<nb, 256, 0, stream>>>(nf, Was, bas, Wms, bms, tab_s);
    hist_k<<<ebk, 256, 0, stream>>>(dst, deg);
    scan_k<<<1, 1024, 0, stream>>>(deg, rowptr, cursor);
    scatter_k<<<ebk, 256, 0, stream>>>(dst, src, cursor, pos, csr_src);
    edge_gemv<<<4096, 256, 0, stream>>>(ef, pos, Wae, bae, Wme, bme, em);
    node_gather2<<<nb, 256, 0, stream>>>(rowptr, csr_src, em, tab_s,
                                         Wad, bad, Wmd, bmd, Wdot, bdot, Wwn, bwn,
                                         nf, (float*)d_out);
}

// Round 12
// 312.354 us; speedup vs baseline: 1.5432x; 1.5075x over previous
//
#include <hip/hip_runtime.h>
#include <hip/hip_bf16.h>

#define V_N 30000
#define E_N 500000

__device__ __forceinline__ float lrelu(float x) { return fmaxf(x, 0.2f * x); }
__device__ __forceinline__ unsigned short f2bf(float f) {
    __hip_bfloat16 h = __float2bfloat16(f);
    return *reinterpret_cast<unsigned short*>(&h);
}
__device__ __forceinline__ float bf_lo(unsigned u) { return __uint_as_float(u << 16); }
__device__ __forceinline__ float bf_hi(unsigned u) { return __uint_as_float(u & 0xffff0000u); }

// ---------------------------------------------------------------------------
// Kernel A: node transforms, streaming at full occupancy.
// Always: src side (Was,Wms) -> tab_s bf16-packed {att01,att23,msg01,msg23}.
// WITH_D: dst side (Wad,Wmd) -> tab_d, same packing (1 uint4/lane/node).
// ---------------------------------------------------------------------------
template<bool WITH_D>
__global__ __launch_bounds__(256) void node_xform_all(
    const float* __restrict__ nf,
    const float* __restrict__ Was, const float* __restrict__ bas,
    const float* __restrict__ Wms, const float* __restrict__ bms,
    const float* __restrict__ Wad, const float* __restrict__ bad,
    const float* __restrict__ Wmd, const float* __restrict__ bmd,
    uint4* __restrict__ tab_s, uint4* __restrict__ tab_d)
{
    __shared__ float w0[1024], w2[1024];
    __shared__ float w13[WITH_D ? 2048 : 2];      // w1 | w3 when WITH_D
    int tid = threadIdx.x;
    for (int i = tid; i < 1024; i += 256) {
        w0[i] = Was[i]; w2[i] = Wms[i];
        if (WITH_D) { w13[i] = Wad[i]; w13[1024 + i] = Wmd[i]; }
    }
    __syncthreads();
    int lane = tid & 31;
    int n = blockIdx.x * 8 + (tid >> 5);          // 3750*8 = 30000 exact
    float sa[4], sm[4], da[4], dm[4];
    #pragma unroll
    for (int h = 0; h < 4; ++h) {
        float x = nf[(size_t)n * 128 + h * 32 + lane];
        float a0 = bas[lane], a2 = bms[lane];
        float a1 = WITH_D ? bad[lane] : 0.f;
        float a3 = WITH_D ? bmd[lane] : 0.f;
        #pragma unroll
        for (int k = 0; k < 32; ++k) {
            float xk = __shfl(x, k, 32);
            a0 = fmaf(xk, w0[k * 32 + lane], a0);
            a2 = fmaf(xk, w2[k * 32 + lane], a2);
            if (WITH_D) {
                a1 = fmaf(xk, w13[k * 32 + lane], a1);
                a3 = fmaf(xk, w13[1024 + k * 32 + lane], a3);
            }
        }
        sa[h] = a0; sm[h] = a2; da[h] = a1; dm[h] = a3;
    }
    uint4 u;
    u.x = f2bf(sa[0]) | ((unsigned)f2bf(sa[1]) << 16);
    u.y = f2bf(sa[2]) | ((unsigned)f2bf(sa[3]) << 16);
    u.z = f2bf(sm[0]) | ((unsigned)f2bf(sm[1]) << 16);
    u.w = f2bf(sm[2]) | ((unsigned)f2bf(sm[3]) << 16);
    tab_s[(size_t)n * 32 + lane] = u;
    if (WITH_D) {
        uint4 v;
        v.x = f2bf(da[0]) | ((unsigned)f2bf(da[1]) << 16);
        v.y = f2bf(da[2]) | ((unsigned)f2bf(da[3]) << 16);
        v.z = f2bf(dm[0]) | ((unsigned)f2bf(dm[1]) << 16);
        v.w = f2bf(dm[2]) | ((unsigned)f2bf(dm[3]) << 16);
        tab_d[(size_t)n * 32 + lane] = v;
    }
}

// ---------------------------------------------------------------------------
// CSR build: histogram -> exclusive scan -> scatter. (R9-proven, verbatim)
// ---------------------------------------------------------------------------
__global__ __launch_bounds__(256) void hist_k(
    const int* __restrict__ dst, int* __restrict__ deg)
{
    int i = blockIdx.x * 256 + threadIdx.x;
    if (i < E_N) atomicAdd(&deg[dst[i]], 1);
}

__global__ __launch_bounds__(1024) void scan_k(
    const int* __restrict__ deg, int* __restrict__ rowptr, int* __restrict__ cursor)
{
    __shared__ int wsum[16];
    __shared__ int carry_s;
    int tid = threadIdx.x;
    int lane = tid & 63, wv = tid >> 6;
    if (tid == 0) carry_s = 0;
    __syncthreads();
    for (int base = 0; base < V_N; base += 1024) {
        int i = base + tid;
        int v = (i < V_N) ? deg[i] : 0;
        int x = v;
        #pragma unroll
        for (int off = 1; off < 64; off <<= 1) {
            int t = __shfl_up(x, off, 64);
            if (lane >= off) x += t;
        }
        if (lane == 63) wsum[wv] = x;
        __syncthreads();
        if (wv == 0 && lane < 16) {
            int s = wsum[lane];
            #pragma unroll
            for (int off = 1; off < 16; off <<= 1) {
                int t = __shfl_up(s, off, 64);
                if (lane >= off) s += t;
            }
            wsum[lane] = s;
        }
        __syncthreads();
        int woff  = (wv == 0) ? 0 : wsum[wv - 1];
        int carry = carry_s;
        int excl  = carry + woff + x - v;
        if (i < V_N) { rowptr[i] = excl; cursor[i] = excl; }
        __syncthreads();
        if (tid == 1023) carry_s = carry + wsum[15];
        __syncthreads();
    }
    if (tid == 0) rowptr[V_N] = carry_s;
}

__global__ __launch_bounds__(256) void scatter_k(
    const int* __restrict__ dst, const int* __restrict__ src,
    int* __restrict__ cursor, int* __restrict__ pos, int* __restrict__ csr_src)
{
    int i = blockIdx.x * 256 + threadIdx.x;
    if (i < E_N) {
        int p = atomicAdd(&cursor[dst[i]], 1);
        pos[i] = p;
        csr_src[p] = src[i];
    }
}

// ---------------------------------------------------------------------------
// Kernel B: STREAMING edge GEMV (coalesced ef, no gathers). (R9-proven)
// ---------------------------------------------------------------------------
__global__ __launch_bounds__(256) void edge_gemv(
    const float* __restrict__ ef, const int* __restrict__ pos,
    const float* __restrict__ Wae, const float* __restrict__ bae,
    const float* __restrict__ Wme, const float* __restrict__ bme,
    unsigned* __restrict__ em)
{
    __shared__ float wa[1024], wm[1024];
    int tid = threadIdx.x;
    for (int i = tid; i < 1024; i += 256) { wa[i] = Wae[i]; wm[i] = Wme[i]; }
    __syncthreads();
    int lane = tid & 31;
    int gid = (blockIdx.x * 256 + tid) >> 5;
    int ngr = (gridDim.x * 256) >> 5;
    float ba = bae[lane], bm = bme[lane];
    for (int e = gid; e < E_N; e += ngr) {
        float x = ef[(size_t)e * 32 + lane];
        int p = pos[e];
        float ea = ba, me = bm;
        #pragma unroll
        for (int k = 0; k < 32; ++k) {
            float xk = __shfl(x, k, 32);
            ea = fmaf(xk, wa[k * 32 + lane], ea);
            me = fmaf(xk, wm[k * 32 + lane], me);
        }
        em[(size_t)p * 32 + lane] = f2bf(ea) | ((unsigned)f2bf(me) << 16);
    }
}

// ---------------------------------------------------------------------------
// Kernel C: per-dst aggregation. R9's depth-1-prefetch loop VERBATIM; slim
// prologue (WITH_D: dst transforms = ONE uint4 load, no GEMVs, no w1/w3 LDS);
// Wwn GEMV moved to the epilogue. Goal: natural VGPR <= ~80, no spills.
// ---------------------------------------------------------------------------
template<bool WITH_D>
__global__ __launch_bounds__(256) void node_gather3(
    const int* __restrict__ rowptr, const int* __restrict__ csr_src,
    const unsigned* __restrict__ em, const uint4* __restrict__ tab_s,
    const uint4* __restrict__ tab_d,
    const float* __restrict__ Wad, const float* __restrict__ bad,
    const float* __restrict__ Wmd, const float* __restrict__ bmd,
    const float* __restrict__ Wdot, const float* __restrict__ bdot,
    const float* __restrict__ Wwn, const float* __restrict__ bwn,
    const float* __restrict__ nf,
    float* __restrict__ out)
{
    __shared__ float ww[1024], wd[32];
    __shared__ float w13[WITH_D ? 2 : 2048];      // fallback-only staging
    int tid = threadIdx.x;
    for (int i = tid; i < 1024; i += 256) {
        ww[i] = Wwn[i];
        if (!WITH_D) { w13[i] = Wad[i]; w13[1024 + i] = Wmd[i]; }
    }
    if (tid < 32) wd[tid] = Wdot[tid];
    __syncthreads();
    int lane = tid & 31;
    int n = blockIdx.x * 8 + (tid >> 5);          // 3750*8 = 30000 exact
    float wdl = wd[lane], bd = bdot[0];

    float da[4], dm[4];
    if (WITH_D) {
        uint4 v = tab_d[(size_t)n * 32 + lane];
        da[0] = bf_lo(v.x); da[1] = bf_hi(v.x);
        da[2] = bf_lo(v.y); da[3] = bf_hi(v.y);
        dm[0] = bf_lo(v.z); dm[1] = bf_hi(v.z);
        dm[2] = bf_lo(v.w); dm[3] = bf_hi(v.w);
    } else {
        #pragma unroll
        for (int h = 0; h < 4; ++h) {
            float x = nf[(size_t)n * 128 + h * 32 + lane];
            float a1 = bad[lane], a3 = bmd[lane];
            #pragma unroll
            for (int k = 0; k < 32; ++k) {
                float xk = __shfl(x, k, 32);
                a1 = fmaf(xk, w13[k * 32 + lane], a1);
                a3 = fmaf(xk, w13[1024 + k * 32 + lane], a3);
            }
            da[h] = a1; dm[h] = a3;
        }
    }

    float acc0 = 0.f, acc1 = 0.f, acc2 = 0.f, acc3 = 0.f;
    float s0 = 0.f, s1 = 0.f, s2 = 0.f, s3 = 0.f;
    int p0 = rowptr[n], p1 = rowptr[n + 1];

    uint4 gc = make_uint4(0, 0, 0, 0);
    unsigned ec = 0;
    if (p0 < p1) {
        int si = csr_src[p0];
        gc = tab_s[(size_t)si * 32 + lane];
        ec = em[(size_t)p0 * 32 + lane];
    }
    for (int p = p0; p < p1; ++p) {
        uint4 g = gc; unsigned ev = ec;
        if (p + 1 < p1) {                          // depth-1 prefetch (R9)
            int sn = csr_src[p + 1];
            gc = tab_s[(size_t)sn * 32 + lane];
            ec = em[(size_t)(p + 1) * 32 + lane];
        }
        float ea = bf_lo(ev), me = bf_hi(ev);
        float t0 = lrelu(bf_lo(g.x) + da[0] + ea) * wdl;
        float t1 = lrelu(bf_hi(g.x) + da[1] + ea) * wdl;
        float t2 = lrelu(bf_lo(g.y) + da[2] + ea) * wdl;
        float t3 = lrelu(bf_hi(g.y) + da[3] + ea) * wdl;
        #pragma unroll
        for (int off = 16; off; off >>= 1) {
            t0 += __shfl_xor(t0, off, 32);
            t1 += __shfl_xor(t1, off, 32);
            t2 += __shfl_xor(t2, off, 32);
            t3 += __shfl_xor(t3, off, 32);
        }
        float x0 = __expf(t0 + bd), x1 = __expf(t1 + bd);
        float x2 = __expf(t2 + bd), x3 = __expf(t3 + bd);
        float m0 = lrelu(bf_lo(g.z) + dm[0] + me);
        float m1 = lrelu(bf_hi(g.z) + dm[1] + me);
        float m2 = lrelu(bf_lo(g.w) + dm[2] + me);
        float m3 = lrelu(bf_hi(g.w) + dm[3] + me);
        acc0 = fmaf(x0, m0, acc0); s0 += x0;
        acc1 = fmaf(x1, m1, acc1); s1 += x1;
        acc2 = fmaf(x2, m2, acc2); s2 += x2;
        acc3 = fmaf(x3, m3, acc3); s3 += x3;
    }
    // epilogue: Wwn GEMV (runs after the hot loop; acc/s pressure released)
    #pragma unroll
    for (int h = 0; h < 4; ++h) {
        float x = nf[(size_t)n * 128 + h * 32 + lane];
        float a = bwn[lane];
        #pragma unroll
        for (int k = 0; k < 32; ++k)
            a = fmaf(__shfl(x, k, 32), ww[k * 32 + lane], a);
        float accv = (h == 0) ? acc0 : (h == 1) ? acc1 : (h == 2) ? acc2 : acc3;
        float sv   = (h == 0) ? s0   : (h == 1) ? s1   : (h == 2) ? s2   : s3;
        float f = (sv > 0.f) ? accv / sv : 0.f;
        out[(size_t)n * 128 + h * 32 + lane] = lrelu(f + a);
    }
}

extern "C" void kernel_launch(void* const* d_in, const int* in_sizes, int n_in,
                              void* d_out, int out_size, void* d_ws, size_t ws_size,
                              hipStream_t stream)
{
    const float* nf  = (const float*)d_in[0];
    const float* ef  = (const float*)d_in[1];
    const int*   src = (const int*)d_in[2];
    const int*   dst = (const int*)d_in[3];
    const float* Was = (const float*)d_in[4],  *bas = (const float*)d_in[5];
    const float* Wad = (const float*)d_in[6],  *bad = (const float*)d_in[7];
    const float* Wae = (const float*)d_in[8],  *bae = (const float*)d_in[9];
    const float* Wdot= (const float*)d_in[10], *bdot= (const float*)d_in[11];
    const float* Wms = (const float*)d_in[12], *bms = (const float*)d_in[13];
    const float* Wmd = (const float*)d_in[14], *bmd = (const float*)d_in[15];
    const float* Wme = (const float*)d_in[16], *bme = (const float*)d_in[17];
    const float* Wwn = (const float*)d_in[18], *bwn = (const float*)d_in[19];

    // layout: em (64 MB) | tab_s (15.36 MB) | [tab_d (15.36 MB)] | ints (~4.4 MB)
    const size_t em_w    = (size_t)E_N * 32;            // u32 words
    const size_t tab_w   = (size_t)V_N * 32;            // uint4 elems
    const size_t int_cnt = (size_t)V_N * 3 + 1 + (size_t)E_N * 2;
    const size_t need_d  = em_w * 4 + tab_w * 16 * 2 + int_cnt * 4;
    const bool   withd   = (ws_size >= need_d);

    unsigned* em    = (unsigned*)d_ws;
    uint4*    tab_s = (uint4*)(em + em_w);
    uint4*    tab_d = withd ? (tab_s + tab_w) : tab_s;  // unused when !withd
    int*      deg   = (int*)(tab_s + (withd ? 2 * tab_w : tab_w));
    int*      rowptr= deg + V_N;
    int*      cursor= rowptr + V_N + 1;
    int*      pos   = cursor + V_N;
    int*      csr_src = pos + E_N;

    hipMemsetAsync(deg, 0, V_N * sizeof(int), stream);

    const int ebk = (E_N + 255) / 256;                  // 1954 blocks
    const int nb  = V_N / 8;                            // 3750 blocks

    if (withd)
        node_xform_all<true><<<nb, 256, 0, stream>>>(nf, Was, bas, Wms, bms,
                                                     Wad, bad, Wmd, bmd, tab_s, tab_d);
    else
        node_xform_all<false><<<nb, 256, 0, stream>>>(nf, Was, bas, Wms, bms,
                                                      Wad, bad, Wmd, bmd, tab_s, tab_d);
    hist_k<<<ebk, 256, 0, stream>>>(dst, deg);
    scan_k<<<1, 1024, 0, stream>>>(deg, rowptr, cursor);
    scatter_k<<<ebk, 256, 0, stream>>>(dst, src, cursor, pos, csr_src);
    edge_gemv<<<4096, 256, 0, stream>>>(ef, pos, Wae, bae, Wme, bme, em);
    if (withd)
        node_gather3<true><<<nb, 256, 0, stream>>>(rowptr, csr_src, em, tab_s, tab_d,
                                                   Wad, bad, Wmd, bmd, Wdot, bdot,
                                                   Wwn, bwn, nf, (float*)d_out);
    else
        node_gather3<false><<<nb, 256, 0, stream>>>(rowptr, csr_src, em, tab_s, tab_d,
                                                    Wad, bad, Wmd, bmd, Wdot, bdot,
                                                    Wwn, bwn, nf, (float*)d_out);
}

// Round 13
// 311.776 us; speedup vs baseline: 1.5460x; 1.0019x over previous
//
#include <hip/hip_runtime.h>
#include <hip/hip_bf16.h>

#define V_N 30000
#define E_N 500000
#define XB  3750                               // xform blocks (V/8)
#define HB  1954                               // hist blocks (ceil(E/256))

__device__ __forceinline__ float lrelu(float x) { return fmaxf(x, 0.2f * x); }
__device__ __forceinline__ unsigned short f2bf(float f) {
    __hip_bfloat16 h = __float2bfloat16(f);
    return *reinterpret_cast<unsigned short*>(&h);
}
__device__ __forceinline__ float bf_lo(unsigned u) { return __uint_as_float(u << 16); }
__device__ __forceinline__ float bf_hi(unsigned u) { return __uint_as_float(u & 0xffff0000u); }

// t + dpp(t); rows excluded by RMASK receive +0 (old=0, bound_ctrl).
template<int CTRL, int RMASK>
__device__ __forceinline__ float dpp_add(float t) {
    int b = __builtin_amdgcn_update_dpp(0, __float_as_int(t), CTRL, RMASK, 0xF, true);
    return t + __int_as_float(b);
}

// Sum over each independent 32-lane group, valid on all 32 lanes.
// VALU-pipe rors + bcast15 + one shfl_xor(16) + select. (R6/R10 numerics-proven)
__device__ __forceinline__ float group_sum(float t, int lane) {
    t = dpp_add<0x121, 0xF>(t);   // row_ror:1
    t = dpp_add<0x122, 0xF>(t);   // row_ror:2
    t = dpp_add<0x124, 0xF>(t);   // row_ror:4
    t = dpp_add<0x128, 0xF>(t);   // row_ror:8  -> each lane = its 16-row sum
    t = dpp_add<0x142, 0xA>(t);   // row_bcast15 -> rows 1,3 hold full 32-sum
    float u = __shfl_xor(t, 16);
    return (lane & 16) ? t : u;
}

// ---------------------------------------------------------------------------
// Kernel A (fused): blocks [0,XB): node transforms (src+dst sides, bf16-packed
// tabs); blocks [XB,XB+HB): dst-degree histogram. (R10 block-split pattern)
// tab layout per node: 32 lanes x uint4 = {att01, att23, msg01, msg23}.
// ---------------------------------------------------------------------------
__global__ __launch_bounds__(256) void xform_hist(
    const float* __restrict__ nf,
    const float* __restrict__ Was, const float* __restrict__ bas,
    const float* __restrict__ Wms, const float* __restrict__ bms,
    const float* __restrict__ Wad, const float* __restrict__ bad,
    const float* __restrict__ Wmd, const float* __restrict__ bmd,
    const int* __restrict__ dst,
    uint4* __restrict__ tab_s, uint4* __restrict__ tab_d, int* __restrict__ deg)
{
    int tid = threadIdx.x;
    if (blockIdx.x >= XB) {                    // histogram part
        int i = (blockIdx.x - XB) * 256 + tid;
        if (i < E_N) atomicAdd(&deg[dst[i]], 1);
        return;
    }
    __shared__ float w0[1024], w2[1024], w1[1024], w3[1024];
    for (int i = tid; i < 1024; i += 256) {
        w0[i] = Was[i]; w2[i] = Wms[i]; w1[i] = Wad[i]; w3[i] = Wmd[i];
    }
    __syncthreads();
    int lane = tid & 31;
    int n = blockIdx.x * 8 + (tid >> 5);       // 3750*8 = 30000 exact
    float sa[4], sm[4], da[4], dm[4];
    #pragma unroll
    for (int h = 0; h < 4; ++h) {
        float x = nf[(size_t)n * 128 + h * 32 + lane];
        float a0 = bas[lane], a2 = bms[lane], a1 = bad[lane], a3 = bmd[lane];
        #pragma unroll
        for (int k = 0; k < 32; ++k) {
            float xk = __shfl(x, k, 32);
            a0 = fmaf(xk, w0[k * 32 + lane], a0);
            a2 = fmaf(xk, w2[k * 32 + lane], a2);
            a1 = fmaf(xk, w1[k * 32 + lane], a1);
            a3 = fmaf(xk, w3[k * 32 + lane], a3);
        }
        sa[h] = a0; sm[h] = a2; da[h] = a1; dm[h] = a3;
    }
    uint4 u;
    u.x = f2bf(sa[0]) | ((unsigned)f2bf(sa[1]) << 16);
    u.y = f2bf(sa[2]) | ((unsigned)f2bf(sa[3]) << 16);
    u.z = f2bf(sm[0]) | ((unsigned)f2bf(sm[1]) << 16);
    u.w = f2bf(sm[2]) | ((unsigned)f2bf(sm[3]) << 16);
    tab_s[(size_t)n * 32 + lane] = u;
    uint4 v;
    v.x = f2bf(da[0]) | ((unsigned)f2bf(da[1]) << 16);
    v.y = f2bf(da[2]) | ((unsigned)f2bf(da[3]) << 16);
    v.z = f2bf(dm[0]) | ((unsigned)f2bf(dm[1]) << 16);
    v.w = f2bf(dm[2]) | ((unsigned)f2bf(dm[3]) << 16);
    tab_d[(size_t)n * 32 + lane] = v;
}

// ---------------------------------------------------------------------------
// Exclusive scan of deg -> rowptr, cursor. (R5-proven, verbatim)
// ---------------------------------------------------------------------------
__global__ __launch_bounds__(1024) void scan_k(
    const int* __restrict__ deg, int* __restrict__ rowptr, int* __restrict__ cursor)
{
    __shared__ int wsum[16];
    __shared__ int carry_s;
    int tid = threadIdx.x;
    int lane = tid & 63, wv = tid >> 6;
    if (tid == 0) carry_s = 0;
    __syncthreads();
    for (int base = 0; base < V_N; base += 1024) {
        int i = base + tid;
        int v = (i < V_N) ? deg[i] : 0;
        int x = v;
        #pragma unroll
        for (int off = 1; off < 64; off <<= 1) {
            int t = __shfl_up(x, off, 64);
            if (lane >= off) x += t;
        }
        if (lane == 63) wsum[wv] = x;
        __syncthreads();
        if (wv == 0 && lane < 16) {
            int s = wsum[lane];
            #pragma unroll
            for (int off = 1; off < 16; off <<= 1) {
                int t = __shfl_up(s, off, 64);
                if (lane >= off) s += t;
            }
            wsum[lane] = s;
        }
        __syncthreads();
        int woff  = (wv == 0) ? 0 : wsum[wv - 1];
        int carry = carry_s;
        int excl  = carry + woff + x - v;
        if (i < V_N) { rowptr[i] = excl; cursor[i] = excl; }
        __syncthreads();
        if (tid == 1023) carry_s = carry + wsum[15];
        __syncthreads();
    }
    if (tid == 0) rowptr[V_N] = carry_s;
}

// ---------------------------------------------------------------------------
// Kernel B (fused scatter + streaming edge GEMV). Group per edge: lane 0
// claims CSR slot p (cursor atomic) + writes csr_src; group computes ea/me
// (shfl+LDS GEMV over coalesced ef) and writes em[p] bf16-packed.
// (R10-proven correctness; removes pos array + one launch vs R12.)
// ---------------------------------------------------------------------------
__global__ __launch_bounds__(256) void scatter_gemv(
    const float* __restrict__ ef, const int* __restrict__ src, const int* __restrict__ dst,
    int* __restrict__ cursor,
    const float* __restrict__ Wae, const float* __restrict__ bae,
    const float* __restrict__ Wme, const float* __restrict__ bme,
    int* __restrict__ csr_src, unsigned* __restrict__ em)
{
    __shared__ float wa[1024], wm[1024];
    int tid = threadIdx.x;
    for (int i = tid; i < 1024; i += 256) { wa[i] = Wae[i]; wm[i] = Wme[i]; }
    __syncthreads();
    int lane = tid & 31;
    int gid = (blockIdx.x * 256 + tid) >> 5;
    int ngr = (gridDim.x * 256) >> 5;
    float ba = bae[lane], bm = bme[lane];
    for (int e = gid; e < E_N; e += ngr) {
        float x = ef[(size_t)e * 32 + lane];
        int p0 = 0;
        if (lane == 0) {
            p0 = atomicAdd(&cursor[dst[e]], 1);
            csr_src[p0] = src[e];
        }
        int p = __shfl(p0, 0, 32);
        float ea = ba, me = bm;
        #pragma unroll
        for (int k = 0; k < 32; ++k) {
            float xk = __shfl(x, k, 32);
            ea = fmaf(xk, wa[k * 32 + lane], ea);
            me = fmaf(xk, wm[k * 32 + lane], me);
        }
        em[(size_t)p * 32 + lane] = f2bf(ea) | ((unsigned)f2bf(me) << 16);
    }
}

// ---------------------------------------------------------------------------
// Kernel C: per-dst aggregation — R12's lean kernel with ONE change:
// butterfly shfl reduce -> DPP group_sum (DS ops/edge 24 -> 4).
// b_dot dropped: exp(t+bd) scales num & denom of alpha identically (exact).
// ---------------------------------------------------------------------------
__global__ __launch_bounds__(256) void node_gather4(
    const int* __restrict__ rowptr, const int* __restrict__ csr_src,
    const unsigned* __restrict__ em, const uint4* __restrict__ tab_s,
    const uint4* __restrict__ tab_d,
    const float* __restrict__ Wdot,
    const float* __restrict__ Wwn, const float* __restrict__ bwn,
    const float* __restrict__ nf,
    float* __restrict__ out)
{
    __shared__ float ww[1024], wd[32];
    int tid = threadIdx.x;
    for (int i = tid; i < 1024; i += 256) ww[i] = Wwn[i];
    if (tid < 32) wd[tid] = Wdot[tid];
    __syncthreads();
    int lane = tid & 31;
    int n = blockIdx.x * 8 + (tid >> 5);       // 3750*8 = 30000 exact
    float wdl = wd[lane];

    float da[4], dm[4];
    {
        uint4 v = tab_d[(size_t)n * 32 + lane];
        da[0] = bf_lo(v.x); da[1] = bf_hi(v.x);
        da[2] = bf_lo(v.y); da[3] = bf_hi(v.y);
        dm[0] = bf_lo(v.z); dm[1] = bf_hi(v.z);
        dm[2] = bf_lo(v.w); dm[3] = bf_hi(v.w);
    }

    float acc0 = 0.f, acc1 = 0.f, acc2 = 0.f, acc3 = 0.f;
    float s0 = 0.f, s1 = 0.f, s2 = 0.f, s3 = 0.f;
    int p0 = rowptr[n], p1 = rowptr[n + 1];

    uint4 gc = make_uint4(0, 0, 0, 0);
    unsigned ec = 0;
    if (p0 < p1) {
        int si = csr_src[p0];
        gc = tab_s[(size_t)si * 32 + lane];
        ec = em[(size_t)p0 * 32 + lane];
    }
    for (int p = p0; p < p1; ++p) {
        uint4 g = gc; unsigned ev = ec;
        if (p + 1 < p1) {                      // depth-1 prefetch
            int sn = csr_src[p + 1];
            gc = tab_s[(size_t)sn * 32 + lane];
            ec = em[(size_t)(p + 1) * 32 + lane];
        }
        float ea = bf_lo(ev), me = bf_hi(ev);
        float t0 = lrelu(bf_lo(g.x) + da[0] + ea) * wdl;
        float t1 = lrelu(bf_hi(g.x) + da[1] + ea) * wdl;
        float t2 = lrelu(bf_lo(g.y) + da[2] + ea) * wdl;
        float t3 = lrelu(bf_hi(g.y) + da[3] + ea) * wdl;
        t0 = group_sum(t0, lane);
        t1 = group_sum(t1, lane);
        t2 = group_sum(t2, lane);
        t3 = group_sum(t3, lane);
        float x0 = __expf(t0), x1 = __expf(t1);
        float x2 = __expf(t2), x3 = __expf(t3);
        float m0 = lrelu(bf_lo(g.z) + dm[0] + me);
        float m1 = lrelu(bf_hi(g.z) + dm[1] + me);
        float m2 = lrelu(bf_lo(g.w) + dm[2] + me);
        float m3 = lrelu(bf_hi(g.w) + dm[3] + me);
        acc0 = fmaf(x0, m0, acc0); s0 += x0;
        acc1 = fmaf(x1, m1, acc1); s1 += x1;
        acc2 = fmaf(x2, m2, acc2); s2 += x2;
        acc3 = fmaf(x3, m3, acc3); s3 += x3;
    }
    // epilogue: Wwn GEMV after acc/s pressure is released
    #pragma unroll
    for (int h = 0; h < 4; ++h) {
        float x = nf[(size_t)n * 128 + h * 32 + lane];
        float a = bwn[lane];
        #pragma unroll
        for (int k = 0; k < 32; ++k)
            a = fmaf(__shfl(x, k, 32), ww[k * 32 + lane], a);
        float accv = (h == 0) ? acc0 : (h == 1) ? acc1 : (h == 2) ? acc2 : acc3;
        float sv   = (h == 0) ? s0   : (h == 1) ? s1   : (h == 2) ? s2   : s3;
        float f = (sv > 0.f) ? accv / sv : 0.f;
        out[(size_t)n * 128 + h * 32 + lane] = lrelu(f + a);
    }
}

extern "C" void kernel_launch(void* const* d_in, const int* in_sizes, int n_in,
                              void* d_out, int out_size, void* d_ws, size_t ws_size,
                              hipStream_t stream)
{
    const float* nf  = (const float*)d_in[0];
    const float* ef  = (const float*)d_in[1];
    const int*   src = (const int*)d_in[2];
    const int*   dst = (const int*)d_in[3];
    const float* Was = (const float*)d_in[4],  *bas = (const float*)d_in[5];
    const float* Wad = (const float*)d_in[6],  *bad = (const float*)d_in[7];
    const float* Wae = (const float*)d_in[8],  *bae = (const float*)d_in[9];
    const float* Wdot= (const float*)d_in[10];
    const float* Wms = (const float*)d_in[12], *bms = (const float*)d_in[13];
    const float* Wmd = (const float*)d_in[14], *bmd = (const float*)d_in[15];
    const float* Wme = (const float*)d_in[16], *bme = (const float*)d_in[17];
    const float* Wwn = (const float*)d_in[18], *bwn = (const float*)d_in[19];

    // ws layout (~97.1 MB; R12 confirmed ws_size covers >= 99.2 MB):
    // em (64 MB) | tab_s (15.36 MB) | tab_d (15.36 MB) | deg,rowptr,cursor,csr_src
    const size_t em_w  = (size_t)E_N * 32;             // u32 words
    const size_t tab_w = (size_t)V_N * 32;             // uint4 elems
    unsigned* em     = (unsigned*)d_ws;
    uint4*    tab_s  = (uint4*)(em + em_w);
    uint4*    tab_d  = tab_s + tab_w;
    int*      deg    = (int*)(tab_d + tab_w);          // V
    int*      rowptr = deg + V_N;                      // V+1
    int*      cursor = rowptr + V_N + 1;               // V
    int*      csr_src= cursor + V_N;                   // E

    hipMemsetAsync(deg, 0, V_N * sizeof(int), stream);

    xform_hist<<<XB + HB, 256, 0, stream>>>(nf, Was, bas, Wms, bms,
                                            Wad, bad, Wmd, bmd, dst,
                                            tab_s, tab_d, deg);
    scan_k<<<1, 1024, 0, stream>>>(deg, rowptr, cursor);
    scatter_gemv<<<4096, 256, 0, stream>>>(ef, src, dst, cursor,
                                           Wae, bae, Wme, bme, csr_src, em);
    node_gather4<<<XB, 256, 0, stream>>>(rowptr, csr_src, em, tab_s, tab_d,
                                         Wdot, Wwn, bwn, nf, (float*)d_out);
}

// Round 14
// 273.374 us; speedup vs baseline: 1.7632x; 1.1405x over previous
//
#include <hip/hip_runtime.h>
#include <hip/hip_bf16.h>

#define V_N 30000
#define E_N 500000
#define XB  3750                               // xform blocks (V/8)
#define HB  1954                               // hist blocks (ceil(E/256))

__device__ __forceinline__ float lrelu(float x) { return fmaxf(x, 0.2f * x); }
__device__ __forceinline__ unsigned short f2bf(float f) {
    __hip_bfloat16 h = __float2bfloat16(f);
    return *reinterpret_cast<unsigned short*>(&h);
}
__device__ __forceinline__ float bf_lo(unsigned u) { return __uint_as_float(u << 16); }
__device__ __forceinline__ float bf_hi(unsigned u) { return __uint_as_float(u & 0xffff0000u); }

// t + dpp(t); rows excluded by RMASK receive +0 (old=0, bound_ctrl).
template<int CTRL, int RMASK>
__device__ __forceinline__ float dpp_add(float t) {
    int b = __builtin_amdgcn_update_dpp(0, __float_as_int(t), CTRL, RMASK, 0xF, true);
    return t + __int_as_float(b);
}

// Sum over each independent 32-lane group, valid on all 32 lanes. (R13-proven)
__device__ __forceinline__ float group_sum(float t, int lane) {
    t = dpp_add<0x121, 0xF>(t);   // row_ror:1
    t = dpp_add<0x122, 0xF>(t);   // row_ror:2
    t = dpp_add<0x124, 0xF>(t);   // row_ror:4
    t = dpp_add<0x128, 0xF>(t);   // row_ror:8  -> each lane = its 16-row sum
    t = dpp_add<0x142, 0xA>(t);   // row_bcast15 -> rows 1,3 hold full 32-sum
    float u = __shfl_xor(t, 16);
    return (lane & 16) ? t : u;
}

// ---------------------------------------------------------------------------
// Kernel A (fused): blocks [0,XB): node transforms (src+dst, bf16-packed tabs);
// blocks [XB,XB+HB): dst-degree histogram. (R13-proven)
// ---------------------------------------------------------------------------
__global__ __launch_bounds__(256) void xform_hist(
    const float* __restrict__ nf,
    const float* __restrict__ Was, const float* __restrict__ bas,
    const float* __restrict__ Wms, const float* __restrict__ bms,
    const float* __restrict__ Wad, const float* __restrict__ bad,
    const float* __restrict__ Wmd, const float* __restrict__ bmd,
    const int* __restrict__ dst,
    uint4* __restrict__ tab_s, uint4* __restrict__ tab_d, int* __restrict__ deg)
{
    int tid = threadIdx.x;
    if (blockIdx.x >= XB) {                    // histogram part
        int i = (blockIdx.x - XB) * 256 + tid;
        if (i < E_N) atomicAdd(&deg[dst[i]], 1);
        return;
    }
    __shared__ float w0[1024], w2[1024], w1[1024], w3[1024];
    for (int i = tid; i < 1024; i += 256) {
        w0[i] = Was[i]; w2[i] = Wms[i]; w1[i] = Wad[i]; w3[i] = Wmd[i];
    }
    __syncthreads();
    int lane = tid & 31;
    int n = blockIdx.x * 8 + (tid >> 5);       // 3750*8 = 30000 exact
    float sa[4], sm[4], da[4], dm[4];
    #pragma unroll
    for (int h = 0; h < 4; ++h) {
        float x = nf[(size_t)n * 128 + h * 32 + lane];
        float a0 = bas[lane], a2 = bms[lane], a1 = bad[lane], a3 = bmd[lane];
        #pragma unroll
        for (int k = 0; k < 32; ++k) {
            float xk = __shfl(x, k, 32);
            a0 = fmaf(xk, w0[k * 32 + lane], a0);
            a2 = fmaf(xk, w2[k * 32 + lane], a2);
            a1 = fmaf(xk, w1[k * 32 + lane], a1);
            a3 = fmaf(xk, w3[k * 32 + lane], a3);
        }
        sa[h] = a0; sm[h] = a2; da[h] = a1; dm[h] = a3;
    }
    uint4 u;
    u.x = f2bf(sa[0]) | ((unsigned)f2bf(sa[1]) << 16);
    u.y = f2bf(sa[2]) | ((unsigned)f2bf(sa[3]) << 16);
    u.z = f2bf(sm[0]) | ((unsigned)f2bf(sm[1]) << 16);
    u.w = f2bf(sm[2]) | ((unsigned)f2bf(sm[3]) << 16);
    tab_s[(size_t)n * 32 + lane] = u;
    uint4 v;
    v.x = f2bf(da[0]) | ((unsigned)f2bf(da[1]) << 16);
    v.y = f2bf(da[2]) | ((unsigned)f2bf(da[3]) << 16);
    v.z = f2bf(dm[0]) | ((unsigned)f2bf(dm[1]) << 16);
    v.w = f2bf(dm[2]) | ((unsigned)f2bf(dm[3]) << 16);
    tab_d[(size_t)n * 32 + lane] = v;
}

// ---------------------------------------------------------------------------
// Exclusive scan of deg -> rowptr, cursor. (R5-proven, verbatim)
// ---------------------------------------------------------------------------
__global__ __launch_bounds__(1024) void scan_k(
    const int* __restrict__ deg, int* __restrict__ rowptr, int* __restrict__ cursor)
{
    __shared__ int wsum[16];
    __shared__ int carry_s;
    int tid = threadIdx.x;
    int lane = tid & 63, wv = tid >> 6;
    if (tid == 0) carry_s = 0;
    __syncthreads();
    for (int base = 0; base < V_N; base += 1024) {
        int i = base + tid;
        int v = (i < V_N) ? deg[i] : 0;
        int x = v;
        #pragma unroll
        for (int off = 1; off < 64; off <<= 1) {
            int t = __shfl_up(x, off, 64);
            if (lane >= off) x += t;
        }
        if (lane == 63) wsum[wv] = x;
        __syncthreads();
        if (wv == 0 && lane < 16) {
            int s = wsum[lane];
            #pragma unroll
            for (int off = 1; off < 16; off <<= 1) {
                int t = __shfl_up(s, off, 64);
                if (lane >= off) s += t;
            }
            wsum[lane] = s;
        }
        __syncthreads();
        int woff  = (wv == 0) ? 0 : wsum[wv - 1];
        int carry = carry_s;
        int excl  = carry + woff + x - v;
        if (i < V_N) { rowptr[i] = excl; cursor[i] = excl; }
        __syncthreads();
        if (tid == 1023) carry_s = carry + wsum[15];
        __syncthreads();
    }
    if (tid == 0) rowptr[V_N] = carry_s;
}

// ---------------------------------------------------------------------------
// Scatter (R12-proven split): atomics only; records pos[e] and csr_src[p].
// Keeping this SEPARATE from the GEMV keeps the 600-cyc atomic RMW out of
// the streaming loop's dependency path (R13 post-mortem).
// ---------------------------------------------------------------------------
__global__ __launch_bounds__(256) void scatter_k(
    const int* __restrict__ dst, const int* __restrict__ src,
    int* __restrict__ cursor, int* __restrict__ pos, int* __restrict__ csr_src)
{
    int i = blockIdx.x * 256 + threadIdx.x;
    if (i < E_N) {
        int p = atomicAdd(&cursor[dst[i]], 1);
        pos[i] = p;
        csr_src[p] = src[i];
    }
}

// ---------------------------------------------------------------------------
// Kernel B: STREAMING edge GEMV (R12-proven): coalesced ef reads, pos[e]
// loaded early (no dependency), em written bf16-packed at CSR slot.
// ---------------------------------------------------------------------------
__global__ __launch_bounds__(256) void edge_gemv(
    const float* __restrict__ ef, const int* __restrict__ pos,
    const float* __restrict__ Wae, const float* __restrict__ bae,
    const float* __restrict__ Wme, const float* __restrict__ bme,
    unsigned* __restrict__ em)
{
    __shared__ float wa[1024], wm[1024];
    int tid = threadIdx.x;
    for (int i = tid; i < 1024; i += 256) { wa[i] = Wae[i]; wm[i] = Wme[i]; }
    __syncthreads();
    int lane = tid & 31;
    int gid = (blockIdx.x * 256 + tid) >> 5;
    int ngr = (gridDim.x * 256) >> 5;
    float ba = bae[lane], bm = bme[lane];
    for (int e = gid; e < E_N; e += ngr) {
        float x = ef[(size_t)e * 32 + lane];
        int p = pos[e];
        float ea = ba, me = bm;
        #pragma unroll
        for (int k = 0; k < 32; ++k) {
            float xk = __shfl(x, k, 32);
            ea = fmaf(xk, wa[k * 32 + lane], ea);
            me = fmaf(xk, wm[k * 32 + lane], me);
        }
        em[(size_t)p * 32 + lane] = f2bf(ea) | ((unsigned)f2bf(me) << 16);
    }
}

// ---------------------------------------------------------------------------
// Kernel C: per-dst aggregation with DPP group_sum. (R13-proven, verbatim)
// b_dot dropped: exp(t+bd) scales num & denom of alpha identically (exact).
// ---------------------------------------------------------------------------
__global__ __launch_bounds__(256) void node_gather4(
    const int* __restrict__ rowptr, const int* __restrict__ csr_src,
    const unsigned* __restrict__ em, const uint4* __restrict__ tab_s,
    const uint4* __restrict__ tab_d,
    const float* __restrict__ Wdot,
    const float* __restrict__ Wwn, const float* __restrict__ bwn,
    const float* __restrict__ nf,
    float* __restrict__ out)
{
    __shared__ float ww[1024], wd[32];
    int tid = threadIdx.x;
    for (int i = tid; i < 1024; i += 256) ww[i] = Wwn[i];
    if (tid < 32) wd[tid] = Wdot[tid];
    __syncthreads();
    int lane = tid & 31;
    int n = blockIdx.x * 8 + (tid >> 5);       // 3750*8 = 30000 exact
    float wdl = wd[lane];

    float da[4], dm[4];
    {
        uint4 v = tab_d[(size_t)n * 32 + lane];
        da[0] = bf_lo(v.x); da[1] = bf_hi(v.x);
        da[2] = bf_lo(v.y); da[3] = bf_hi(v.y);
        dm[0] = bf_lo(v.z); dm[1] = bf_hi(v.z);
        dm[2] = bf_lo(v.w); dm[3] = bf_hi(v.w);
    }

    float acc0 = 0.f, acc1 = 0.f, acc2 = 0.f, acc3 = 0.f;
    float s0 = 0.f, s1 = 0.f, s2 = 0.f, s3 = 0.f;
    int p0 = rowptr[n], p1 = rowptr[n + 1];

    uint4 gc = make_uint4(0, 0, 0, 0);
    unsigned ec = 0;
    if (p0 < p1) {
        int si = csr_src[p0];
        gc = tab_s[(size_t)si * 32 + lane];
        ec = em[(size_t)p0 * 32 + lane];
    }
    for (int p = p0; p < p1; ++p) {
        uint4 g = gc; unsigned ev = ec;
        if (p + 1 < p1) {                      // depth-1 prefetch
            int sn = csr_src[p + 1];
            gc = tab_s[(size_t)sn * 32 + lane];
            ec = em[(size_t)(p + 1) * 32 + lane];
        }
        float ea = bf_lo(ev), me = bf_hi(ev);
        float t0 = lrelu(bf_lo(g.x) + da[0] + ea) * wdl;
        float t1 = lrelu(bf_hi(g.x) + da[1] + ea) * wdl;
        float t2 = lrelu(bf_lo(g.y) + da[2] + ea) * wdl;
        float t3 = lrelu(bf_hi(g.y) + da[3] + ea) * wdl;
        t0 = group_sum(t0, lane);
        t1 = group_sum(t1, lane);
        t2 = group_sum(t2, lane);
        t3 = group_sum(t3, lane);
        float x0 = __expf(t0), x1 = __expf(t1);
        float x2 = __expf(t2), x3 = __expf(t3);
        float m0 = lrelu(bf_lo(g.z) + dm[0] + me);
        float m1 = lrelu(bf_hi(g.z) + dm[1] + me);
        float m2 = lrelu(bf_lo(g.w) + dm[2] + me);
        float m3 = lrelu(bf_hi(g.w) + dm[3] + me);
        acc0 = fmaf(x0, m0, acc0); s0 += x0;
        acc1 = fmaf(x1, m1, acc1); s1 += x1;
        acc2 = fmaf(x2, m2, acc2); s2 += x2;
        acc3 = fmaf(x3, m3, acc3); s3 += x3;
    }
    // epilogue: Wwn GEMV after acc/s pressure is released
    #pragma unroll
    for (int h = 0; h < 4; ++h) {
        float x = nf[(size_t)n * 128 + h * 32 + lane];
        float a = bwn[lane];
        #pragma unroll
        for (int k = 0; k < 32; ++k)
            a = fmaf(__shfl(x, k, 32), ww[k * 32 + lane], a);
        float accv = (h == 0) ? acc0 : (h == 1) ? acc1 : (h == 2) ? acc2 : acc3;
        float sv   = (h == 0) ? s0   : (h == 1) ? s1   : (h == 2) ? s2   : s3;
        float f = (sv > 0.f) ? accv / sv : 0.f;
        out[(size_t)n * 128 + h * 32 + lane] = lrelu(f + a);
    }
}

extern "C" void kernel_launch(void* const* d_in, const int* in_sizes, int n_in,
                              void* d_out, int out_size, void* d_ws, size_t ws_size,
                              hipStream_t stream)
{
    const float* nf  = (const float*)d_in[0];
    const float* ef  = (const float*)d_in[1];
    const int*   src = (const int*)d_in[2];
    const int*   dst = (const int*)d_in[3];
    const float* Was = (const float*)d_in[4],  *bas = (const float*)d_in[5];
    const float* Wad = (const float*)d_in[6],  *bad = (const float*)d_in[7];
    const float* Wae = (const float*)d_in[8],  *bae = (const float*)d_in[9];
    const float* Wdot= (const float*)d_in[10];
    const float* Wms = (const float*)d_in[12], *bms = (const float*)d_in[13];
    const float* Wmd = (const float*)d_in[14], *bmd = (const float*)d_in[15];
    const float* Wme = (const float*)d_in[16], *bme = (const float*)d_in[17];
    const float* Wwn = (const float*)d_in[18], *bwn = (const float*)d_in[19];

    // ws layout (~99.1 MB, fits: R9/R12 proven >= 99.2 MB available):
    // em (64 MB) | tab_s (15.36) | tab_d (15.36) | deg,rowptr,cursor | pos,csr_src
    const size_t em_w  = (size_t)E_N * 32;             // u32 words
    const size_t tab_w = (size_t)V_N * 32;             // uint4 elems
    unsigned* em     = (unsigned*)d_ws;
    uint4*    tab_s  = (uint4*)(em + em_w);
    uint4*    tab_d  = tab_s + tab_w;
    int*      deg    = (int*)(tab_d + tab_w);          // V
    int*      rowptr = deg + V_N;                      // V+1
    int*      cursor = rowptr + V_N + 1;               // V
    int*      pos    = cursor + V_N;                   // E
    int*      csr_src= pos + E_N;                      // E

    hipMemsetAsync(deg, 0, V_N * sizeof(int), stream);

    const int ebk = (E_N + 255) / 256;                 // 1954 blocks

    xform_hist<<<XB + HB, 256, 0, stream>>>(nf, Was, bas, Wms, bms,
                                            Wad, bad, Wmd, bmd, dst,
                                            tab_s, tab_d, deg);
    scan_k<<<1, 1024, 0, stream>>>(deg, rowptr, cursor);
    scatter_k<<<ebk, 256, 0, stream>>>(dst, src, cursor, pos, csr_src);
    edge_gemv<<<4096, 256, 0, stream>>>(ef, pos, Wae, bae, Wme, bme, em);
    node_gather4<<<XB, 256, 0, stream>>>(rowptr, csr_src, em, tab_s, tab_d,
                                         Wdot, Wwn, bwn, nf, (float*)d_out);
}

// Round 15
// 205.176 us; speedup vs baseline: 2.3493x; 1.3324x over previous
//
#include <hip/hip_runtime.h>
#include <hip/hip_bf16.h>

#define V_N 30000
#define E_N 500000
#define XB  3750                               // xform blocks (V/8)
#define HB  1954                               // hist blocks (ceil(E/256))

typedef __attribute__((ext_vector_type(8))) short bf16x8;
typedef __attribute__((ext_vector_type(4))) float f32x4;

__device__ __forceinline__ float lrelu(float x) { return fmaxf(x, 0.2f * x); }
__device__ __forceinline__ unsigned short f2bf(float f) {
    __hip_bfloat16 h = __float2bfloat16(f);
    return *reinterpret_cast<unsigned short*>(&h);
}
__device__ __forceinline__ float bf_lo(unsigned u) { return __uint_as_float(u << 16); }
__device__ __forceinline__ float bf_hi(unsigned u) { return __uint_as_float(u & 0xffff0000u); }

// t + dpp(t); rows excluded by RMASK receive +0 (old=0, bound_ctrl).
template<int CTRL, int RMASK>
__device__ __forceinline__ float dpp_add(float t) {
    int b = __builtin_amdgcn_update_dpp(0, __float_as_int(t), CTRL, RMASK, 0xF, true);
    return t + __int_as_float(b);
}

// Sum over each independent 32-lane group, valid on all 32 lanes. (R13-proven)
__device__ __forceinline__ float group_sum(float t, int lane) {
    t = dpp_add<0x121, 0xF>(t);   // row_ror:1
    t = dpp_add<0x122, 0xF>(t);   // row_ror:2
    t = dpp_add<0x124, 0xF>(t);   // row_ror:4
    t = dpp_add<0x128, 0xF>(t);   // row_ror:8  -> each lane = its 16-row sum
    t = dpp_add<0x142, 0xA>(t);   // row_bcast15 -> rows 1,3 hold full 32-sum
    float u = __shfl_xor(t, 16);
    return (lane & 16) ? t : u;
}

// ---------------------------------------------------------------------------
// Kernel A (fused): blocks [0,XB): node transforms (src+dst, bf16-packed tabs);
// blocks [XB,XB+HB): dst-degree histogram. (R13/R14-proven, verbatim)
// ---------------------------------------------------------------------------
__global__ __launch_bounds__(256) void xform_hist(
    const float* __restrict__ nf,
    const float* __restrict__ Was, const float* __restrict__ bas,
    const float* __restrict__ Wms, const float* __restrict__ bms,
    const float* __restrict__ Wad, const float* __restrict__ bad,
    const float* __restrict__ Wmd, const float* __restrict__ bmd,
    const int* __restrict__ dst,
    uint4* __restrict__ tab_s, uint4* __restrict__ tab_d, int* __restrict__ deg)
{
    int tid = threadIdx.x;
    if (blockIdx.x >= XB) {                    // histogram part
        int i = (blockIdx.x - XB) * 256 + tid;
        if (i < E_N) atomicAdd(&deg[dst[i]], 1);
        return;
    }
    __shared__ float w0[1024], w2[1024], w1[1024], w3[1024];
    for (int i = tid; i < 1024; i += 256) {
        w0[i] = Was[i]; w2[i] = Wms[i]; w1[i] = Wad[i]; w3[i] = Wmd[i];
    }
    __syncthreads();
    int lane = tid & 31;
    int n = blockIdx.x * 8 + (tid >> 5);       // 3750*8 = 30000 exact
    float sa[4], sm[4], da[4], dm[4];
    #pragma unroll
    for (int h = 0; h < 4; ++h) {
        float x = nf[(size_t)n * 128 + h * 32 + lane];
        float a0 = bas[lane], a2 = bms[lane], a1 = bad[lane], a3 = bmd[lane];
        #pragma unroll
        for (int k = 0; k < 32; ++k) {
            float xk = __shfl(x, k, 32);
            a0 = fmaf(xk, w0[k * 32 + lane], a0);
            a2 = fmaf(xk, w2[k * 32 + lane], a2);
            a1 = fmaf(xk, w1[k * 32 + lane], a1);
            a3 = fmaf(xk, w3[k * 32 + lane], a3);
        }
        sa[h] = a0; sm[h] = a2; da[h] = a1; dm[h] = a3;
    }
    uint4 u;
    u.x = f2bf(sa[0]) | ((unsigned)f2bf(sa[1]) << 16);
    u.y = f2bf(sa[2]) | ((unsigned)f2bf(sa[3]) << 16);
    u.z = f2bf(sm[0]) | ((unsigned)f2bf(sm[1]) << 16);
    u.w = f2bf(sm[2]) | ((unsigned)f2bf(sm[3]) << 16);
    tab_s[(size_t)n * 32 + lane] = u;
    uint4 v;
    v.x = f2bf(da[0]) | ((unsigned)f2bf(da[1]) << 16);
    v.y = f2bf(da[2]) | ((unsigned)f2bf(da[3]) << 16);
    v.z = f2bf(dm[0]) | ((unsigned)f2bf(dm[1]) << 16);
    v.w = f2bf(dm[2]) | ((unsigned)f2bf(dm[3]) << 16);
    tab_d[(size_t)n * 32 + lane] = v;
}

// ---------------------------------------------------------------------------
// Exclusive scan of deg -> rowptr, cursor. (R5-proven, verbatim)
// ---------------------------------------------------------------------------
__global__ __launch_bounds__(1024) void scan_k(
    const int* __restrict__ deg, int* __restrict__ rowptr, int* __restrict__ cursor)
{
    __shared__ int wsum[16];
    __shared__ int carry_s;
    int tid = threadIdx.x;
    int lane = tid & 63, wv = tid >> 6;
    if (tid == 0) carry_s = 0;
    __syncthreads();
    for (int base = 0; base < V_N; base += 1024) {
        int i = base + tid;
        int v = (i < V_N) ? deg[i] : 0;
        int x = v;
        #pragma unroll
        for (int off = 1; off < 64; off <<= 1) {
            int t = __shfl_up(x, off, 64);
            if (lane >= off) x += t;
        }
        if (lane == 63) wsum[wv] = x;
        __syncthreads();
        if (wv == 0 && lane < 16) {
            int s = wsum[lane];
            #pragma unroll
            for (int off = 1; off < 16; off <<= 1) {
                int t = __shfl_up(s, off, 64);
                if (lane >= off) s += t;
            }
            wsum[lane] = s;
        }
        __syncthreads();
        int woff  = (wv == 0) ? 0 : wsum[wv - 1];
        int carry = carry_s;
        int excl  = carry + woff + x - v;
        if (i < V_N) { rowptr[i] = excl; cursor[i] = excl; }
        __syncthreads();
        if (tid == 1023) carry_s = carry + wsum[15];
        __syncthreads();
    }
    if (tid == 0) rowptr[V_N] = carry_s;
}

// ---------------------------------------------------------------------------
// Scatter (R12/R14-proven split): atomics only; pos[e] and csr_src[p].
// ---------------------------------------------------------------------------
__global__ __launch_bounds__(256) void scatter_k(
    const int* __restrict__ dst, const int* __restrict__ src,
    int* __restrict__ cursor, int* __restrict__ pos, int* __restrict__ csr_src)
{
    int i = blockIdx.x * 256 + threadIdx.x;
    if (i < E_N) {
        int p = atomicAdd(&cursor[dst[i]], 1);
        pos[i] = p;
        csr_src[p] = src[i];
    }
}

// ---------------------------------------------------------------------------
// Kernel B: MFMA edge GEMV. One wave64 = 16 edges.
//   A (16 edges x 32 feats, bf16): lane l holds row (l&15), k = (l>>4)*8..+7
//   B (32 x 16 cols, bf16): 4 fragments = [Wae|Wme] cols 0-15/16-31 each;
//       lane l holds B[k= (l>>4)*8+i][col=(l&15)]
//   D (16x16 f32): lane l holds D[row=(l>>4)*4+j][col=l&15]  (m89-verified)
// Epilogue: +bias in f32, pack bf16 {ea|me}, write em[pos[e]] (128B/edge).
// ---------------------------------------------------------------------------
__global__ __launch_bounds__(256) void edge_gemv_mfma(
    const float* __restrict__ ef, const int* __restrict__ pos,
    const float* __restrict__ Wae, const float* __restrict__ bae,
    const float* __restrict__ Wme, const float* __restrict__ bme,
    unsigned* __restrict__ em)
{
    int tid  = threadIdx.x;
    int lane = tid & 63;
    int l15  = lane & 15, q = lane >> 4;       // quarter 0..3
    // preload B fragments (one-time): t0=Wae[:,0:16] t1=Wae[:,16:32]
    //                                 t2=Wme[:,0:16] t3=Wme[:,16:32]
    bf16x8 B0, B1, B2, B3;
    #pragma unroll
    for (int i = 0; i < 8; ++i) {
        int k = q * 8 + i;
        B0[i] = (short)f2bf(Wae[k * 32 + l15]);
        B1[i] = (short)f2bf(Wae[k * 32 + 16 + l15]);
        B2[i] = (short)f2bf(Wme[k * 32 + l15]);
        B3[i] = (short)f2bf(Wme[k * 32 + 16 + l15]);
    }
    float ba0 = bae[l15], ba1 = bae[16 + l15];
    float bm0 = bme[l15], bm1 = bme[16 + l15];

    int wid = (blockIdx.x * 256 + tid) >> 6;
    int nw  = (gridDim.x * 256) >> 6;
    const int ntiles = E_N / 16;               // 31250 exact
    for (int tile = wid; tile < ntiles; tile += nw) {
        int ebase = tile * 16;
        // A fragment: two float4 loads, convert to bf16
        const float4* ap = (const float4*)(ef + (size_t)(ebase + l15) * 32 + q * 8);
        float4 a0 = ap[0], a1 = ap[1];
        int pv = pos[ebase + l15];
        bf16x8 A;
        A[0] = (short)f2bf(a0.x); A[1] = (short)f2bf(a0.y);
        A[2] = (short)f2bf(a0.z); A[3] = (short)f2bf(a0.w);
        A[4] = (short)f2bf(a1.x); A[5] = (short)f2bf(a1.y);
        A[6] = (short)f2bf(a1.z); A[7] = (short)f2bf(a1.w);
        f32x4 z = {0.f, 0.f, 0.f, 0.f};
        f32x4 D0 = __builtin_amdgcn_mfma_f32_16x16x32_bf16(A, B0, z, 0, 0, 0);
        f32x4 D1 = __builtin_amdgcn_mfma_f32_16x16x32_bf16(A, B1, z, 0, 0, 0);
        f32x4 D2 = __builtin_amdgcn_mfma_f32_16x16x32_bf16(A, B2, z, 0, 0, 0);
        f32x4 D3 = __builtin_amdgcn_mfma_f32_16x16x32_bf16(A, B3, z, 0, 0, 0);
        #pragma unroll
        for (int j = 0; j < 4; ++j) {
            int r = q * 4 + j;                 // edge row this lane holds
            int p = __shfl(pv, r, 64);         // pos[ebase + r]
            unsigned lo = f2bf(D0[j] + ba0) | ((unsigned)f2bf(D2[j] + bm0) << 16);
            unsigned hi = f2bf(D1[j] + ba1) | ((unsigned)f2bf(D3[j] + bm1) << 16);
            em[(size_t)p * 32 + l15]      = lo;
            em[(size_t)p * 32 + 16 + l15] = hi;
        }
    }
}

// ---------------------------------------------------------------------------
// Kernel C: per-dst aggregation with DPP group_sum. (R13/R14-proven, verbatim)
// b_dot dropped: exp(t+bd) scales num & denom of alpha identically (exact).
// ---------------------------------------------------------------------------
__global__ __launch_bounds__(256) void node_gather4(
    const int* __restrict__ rowptr, const int* __restrict__ csr_src,
    const unsigned* __restrict__ em, const uint4* __restrict__ tab_s,
    const uint4* __restrict__ tab_d,
    const float* __restrict__ Wdot,
    const float* __restrict__ Wwn, const float* __restrict__ bwn,
    const float* __restrict__ nf,
    float* __restrict__ out)
{
    __shared__ float ww[1024], wd[32];
    int tid = threadIdx.x;
    for (int i = tid; i < 1024; i += 256) ww[i] = Wwn[i];
    if (tid < 32) wd[tid] = Wdot[tid];
    __syncthreads();
    int lane = tid & 31;
    int n = blockIdx.x * 8 + (tid >> 5);       // 3750*8 = 30000 exact
    float wdl = wd[lane];

    float da[4], dm[4];
    {
        uint4 v = tab_d[(size_t)n * 32 + lane];
        da[0] = bf_lo(v.x); da[1] = bf_hi(v.x);
        da[2] = bf_lo(v.y); da[3] = bf_hi(v.y);
        dm[0] = bf_lo(v.z); dm[1] = bf_hi(v.z);
        dm[2] = bf_lo(v.w); dm[3] = bf_hi(v.w);
    }

    float acc0 = 0.f, acc1 = 0.f, acc2 = 0.f, acc3 = 0.f;
    float s0 = 0.f, s1 = 0.f, s2 = 0.f, s3 = 0.f;
    int p0 = rowptr[n], p1 = rowptr[n + 1];

    uint4 gc = make_uint4(0, 0, 0, 0);
    unsigned ec = 0;
    if (p0 < p1) {
        int si = csr_src[p0];
        gc = tab_s[(size_t)si * 32 + lane];
        ec = em[(size_t)p0 * 32 + lane];
    }
    for (int p = p0; p < p1; ++p) {
        uint4 g = gc; unsigned ev = ec;
        if (p + 1 < p1) {                      // depth-1 prefetch
            int sn = csr_src[p + 1];
            gc = tab_s[(size_t)sn * 32 + lane];
            ec = em[(size_t)(p + 1) * 32 + lane];
        }
        float ea = bf_lo(ev), me = bf_hi(ev);
        float t0 = lrelu(bf_lo(g.x) + da[0] + ea) * wdl;
        float t1 = lrelu(bf_hi(g.x) + da[1] + ea) * wdl;
        float t2 = lrelu(bf_lo(g.y) + da[2] + ea) * wdl;
        float t3 = lrelu(bf_hi(g.y) + da[3] + ea) * wdl;
        t0 = group_sum(t0, lane);
        t1 = group_sum(t1, lane);
        t2 = group_sum(t2, lane);
        t3 = group_sum(t3, lane);
        float x0 = __expf(t0), x1 = __expf(t1);
        float x2 = __expf(t2), x3 = __expf(t3);
        float m0 = lrelu(bf_lo(g.z) + dm[0] + me);
        float m1 = lrelu(bf_hi(g.z) + dm[1] + me);
        float m2 = lrelu(bf_lo(g.w) + dm[2] + me);
        float m3 = lrelu(bf_hi(g.w) + dm[3] + me);
        acc0 = fmaf(x0, m0, acc0); s0 += x0;
        acc1 = fmaf(x1, m1, acc1); s1 += x1;
        acc2 = fmaf(x2, m2, acc2); s2 += x2;
        acc3 = fmaf(x3, m3, acc3); s3 += x3;
    }
    // epilogue: Wwn GEMV after acc/s pressure is released
    #pragma unroll
    for (int h = 0; h < 4; ++h) {
        float x = nf[(size_t)n * 128 + h * 32 + lane];
        float a = bwn[lane];
        #pragma unroll
        for (int k = 0; k < 32; ++k)
            a = fmaf(__shfl(x, k, 32), ww[k * 32 + lane], a);
        float accv = (h == 0) ? acc0 : (h == 1) ? acc1 : (h == 2) ? acc2 : acc3;
        float sv   = (h == 0) ? s0   : (h == 1) ? s1   : (h == 2) ? s2   : s3;
        float f = (sv > 0.f) ? accv / sv : 0.f;
        out[(size_t)n * 128 + h * 32 + lane] = lrelu(f + a);
    }
}

extern "C" void kernel_launch(void* const* d_in, const int* in_sizes, int n_in,
                              void* d_out, int out_size, void* d_ws, size_t ws_size,
                              hipStream_t stream)
{
    const float* nf  = (const float*)d_in[0];
    const float* ef  = (const float*)d_in[1];
    const int*   src = (const int*)d_in[2];
    const int*   dst = (const int*)d_in[3];
    const float* Was = (const float*)d_in[4],  *bas = (const float*)d_in[5];
    const float* Wad = (const float*)d_in[6],  *bad = (const float*)d_in[7];
    const float* Wae = (const float*)d_in[8],  *bae = (const float*)d_in[9];
    const float* Wdot= (const float*)d_in[10];
    const float* Wms = (const float*)d_in[12], *bms = (const float*)d_in[13];
    const float* Wmd = (const float*)d_in[14], *bmd = (const float*)d_in[15];
    const float* Wme = (const float*)d_in[16], *bme = (const float*)d_in[17];
    const float* Wwn = (const float*)d_in[18], *bwn = (const float*)d_in[19];

    // ws layout (~99.1 MB): em (64) | tab_s (15.36) | tab_d (15.36) | ints
    const size_t em_w  = (size_t)E_N * 32;             // u32 words
    const size_t tab_w = (size_t)V_N * 32;             // uint4 elems
    unsigned* em     = (unsigned*)d_ws;
    uint4*    tab_s  = (uint4*)(em + em_w);
    uint4*    tab_d  = tab_s + tab_w;
    int*      deg    = (int*)(tab_d + tab_w);          // V
    int*      rowptr = deg + V_N;                      // V+1
    int*      cursor = rowptr + V_N + 1;               // V
    int*      pos    = cursor + V_N;                   // E
    int*      csr_src= pos + E_N;                      // E

    hipMemsetAsync(deg, 0, V_N * sizeof(int), stream);

    const int ebk = (E_N + 255) / 256;                 // 1954 blocks

    xform_hist<<<XB + HB, 256, 0, stream>>>(nf, Was, bas, Wms, bms,
                                            Wad, bad, Wmd, bmd, dst,
                                            tab_s, tab_d, deg);
    scan_k<<<1, 1024, 0, stream>>>(deg, rowptr, cursor);
    scatter_k<<<ebk, 256, 0, stream>>>(dst, src, cursor, pos, csr_src);
    edge_gemv_mfma<<<2048, 256, 0, stream>>>(ef, pos, Wae, bae, Wme, bme, em);
    node_gather4<<<XB, 256, 0, stream>>>(rowptr, csr_src, em, tab_s, tab_d,
                                         Wdot, Wwn, bwn, nf, (float*)d_out);
}

// Round 16
// 187.167 us; speedup vs baseline: 2.5753x; 1.0962x over previous
//
#include <hip/hip_runtime.h>
#include <hip/hip_bf16.h>

#define V_N 30000
#define E_N 500000
#define XW  512                                // xform blocks (grid-stride)
#define HB  1954                               // hist blocks (ceil(E/256))

typedef __attribute__((ext_vector_type(8))) short bf16x8;
typedef __attribute__((ext_vector_type(4))) float f32x4;

__device__ __forceinline__ float lrelu(float x) { return fmaxf(x, 0.2f * x); }
__device__ __forceinline__ unsigned short f2bf(float f) {
    __hip_bfloat16 h = __float2bfloat16(f);
    return *reinterpret_cast<unsigned short*>(&h);
}
__device__ __forceinline__ float bf_lo(unsigned u) { return __uint_as_float(u << 16); }
__device__ __forceinline__ float bf_hi(unsigned u) { return __uint_as_float(u & 0xffff0000u); }

// t + dpp(t); rows excluded by RMASK receive +0 (old=0, bound_ctrl).
template<int CTRL, int RMASK>
__device__ __forceinline__ float dpp_add(float t) {
    int b = __builtin_amdgcn_update_dpp(0, __float_as_int(t), CTRL, RMASK, 0xF, true);
    return t + __int_as_float(b);
}

// Sum over each independent 32-lane group, valid on all 32 lanes. (R13-proven)
__device__ __forceinline__ float group_sum(float t, int lane) {
    t = dpp_add<0x121, 0xF>(t);   // row_ror:1
    t = dpp_add<0x122, 0xF>(t);   // row_ror:2
    t = dpp_add<0x124, 0xF>(t);   // row_ror:4
    t = dpp_add<0x128, 0xF>(t);   // row_ror:8  -> each lane = its 16-row sum
    t = dpp_add<0x142, 0xA>(t);   // row_bcast15 -> rows 1,3 hold full 32-sum
    float u = __shfl_xor(t, 16);
    return (lane & 16) ? t : u;
}

// ---------------------------------------------------------------------------
// Kernel A (fused): blocks [0,XW): MFMA node transforms (grid-stride tiles);
// blocks [XW,XW+HB): dst-degree histogram.
// One wave64 tile = 16 node-head rows = 4 nodes. 8 MFMAs cover the 128
// output cols of [Was|Wad|Wms|Wmd]. D row map (l>>4)*4+j puts ALL 4 HEADS of
// node (l>>4) on lane l at feature col (l&15) -> packs to tab layout with
// zero cross-lane traffic. Layouts HW-verified by R15's edge_gemv_mfma.
// ---------------------------------------------------------------------------
__global__ __launch_bounds__(256) void xform_hist_mfma(
    const float* __restrict__ nf,
    const float* __restrict__ Was, const float* __restrict__ bas,
    const float* __restrict__ Wms, const float* __restrict__ bms,
    const float* __restrict__ Wad, const float* __restrict__ bad,
    const float* __restrict__ Wmd, const float* __restrict__ bmd,
    const int* __restrict__ dst,
    uint4* __restrict__ tab_s, uint4* __restrict__ tab_d, int* __restrict__ deg)
{
    int tid = threadIdx.x;
    if (blockIdx.x >= XW) {                    // histogram part
        int i = (blockIdx.x - XW) * 256 + tid;
        if (i < E_N) atomicAdd(&deg[dst[i]], 1);
        return;
    }
    int lane = tid & 63;
    int l15 = lane & 15, q = lane >> 4;        // quarter 0..3
    // B fragments: 4 matrices x 2 col-halves. lane l: B[k=(q*8+i)][col]
    bf16x8 Bas0, Bas1, Bad0, Bad1, Bms0, Bms1, Bmd0, Bmd1;
    #pragma unroll
    for (int i = 0; i < 8; ++i) {
        int k = q * 8 + i;
        Bas0[i] = (short)f2bf(Was[k * 32 + l15]);
        Bas1[i] = (short)f2bf(Was[k * 32 + 16 + l15]);
        Bad0[i] = (short)f2bf(Wad[k * 32 + l15]);
        Bad1[i] = (short)f2bf(Wad[k * 32 + 16 + l15]);
        Bms0[i] = (short)f2bf(Wms[k * 32 + l15]);
        Bms1[i] = (short)f2bf(Wms[k * 32 + 16 + l15]);
        Bmd0[i] = (short)f2bf(Wmd[k * 32 + l15]);
        Bmd1[i] = (short)f2bf(Wmd[k * 32 + 16 + l15]);
    }
    float bs0 = bas[l15], bs1 = bas[16 + l15];
    float bd0 = bad[l15], bd1 = bad[16 + l15];
    float bm0 = bms[l15], bm1 = bms[16 + l15];
    float bn0 = bmd[l15], bn1 = bmd[16 + l15];

    int wv = tid >> 6;                         // wave in block (0..3)
    const int ntiles = V_N / 4;                // 7500 (4 nodes per tile)
    for (int tile = blockIdx.x * 4 + wv; tile < ntiles; tile += XW * 4) {
        int nbase = tile * 4;
        int rbase = nbase * 4;                 // 16 node-head rows
        const float4* ap = (const float4*)(nf + (size_t)(rbase + l15) * 32 + q * 8);
        float4 a0 = ap[0], a1 = ap[1];
        bf16x8 A;
        A[0] = (short)f2bf(a0.x); A[1] = (short)f2bf(a0.y);
        A[2] = (short)f2bf(a0.z); A[3] = (short)f2bf(a0.w);
        A[4] = (short)f2bf(a1.x); A[5] = (short)f2bf(a1.y);
        A[6] = (short)f2bf(a1.z); A[7] = (short)f2bf(a1.w);
        f32x4 z = {0.f, 0.f, 0.f, 0.f};
        f32x4 Das0 = __builtin_amdgcn_mfma_f32_16x16x32_bf16(A, Bas0, z, 0, 0, 0);
        f32x4 Das1 = __builtin_amdgcn_mfma_f32_16x16x32_bf16(A, Bas1, z, 0, 0, 0);
        f32x4 Dad0 = __builtin_amdgcn_mfma_f32_16x16x32_bf16(A, Bad0, z, 0, 0, 0);
        f32x4 Dad1 = __builtin_amdgcn_mfma_f32_16x16x32_bf16(A, Bad1, z, 0, 0, 0);
        f32x4 Dms0 = __builtin_amdgcn_mfma_f32_16x16x32_bf16(A, Bms0, z, 0, 0, 0);
        f32x4 Dms1 = __builtin_amdgcn_mfma_f32_16x16x32_bf16(A, Bms1, z, 0, 0, 0);
        f32x4 Dmd0 = __builtin_amdgcn_mfma_f32_16x16x32_bf16(A, Bmd0, z, 0, 0, 0);
        f32x4 Dmd1 = __builtin_amdgcn_mfma_f32_16x16x32_bf16(A, Bmd1, z, 0, 0, 0);
        // lane l holds node (nbase+q), heads j=0..3, feature col l15 / 16+l15
        int node = nbase + q;
        uint4 lo, hi;
        lo.x = f2bf(Das0[0] + bs0) | ((unsigned)f2bf(Das0[1] + bs0) << 16);
        lo.y = f2bf(Das0[2] + bs0) | ((unsigned)f2bf(Das0[3] + bs0) << 16);
        lo.z = f2bf(Dms0[0] + bm0) | ((unsigned)f2bf(Dms0[1] + bm0) << 16);
        lo.w = f2bf(Dms0[2] + bm0) | ((unsigned)f2bf(Dms0[3] + bm0) << 16);
        hi.x = f2bf(Das1[0] + bs1) | ((unsigned)f2bf(Das1[1] + bs1) << 16);
        hi.y = f2bf(Das1[2] + bs1) | ((unsigned)f2bf(Das1[3] + bs1) << 16);
        hi.z = f2bf(Dms1[0] + bm1) | ((unsigned)f2bf(Dms1[1] + bm1) << 16);
        hi.w = f2bf(Dms1[2] + bm1) | ((unsigned)f2bf(Dms1[3] + bm1) << 16);
        tab_s[(size_t)node * 32 + l15]      = lo;
        tab_s[(size_t)node * 32 + 16 + l15] = hi;
        uint4 lod, hid;
        lod.x = f2bf(Dad0[0] + bd0) | ((unsigned)f2bf(Dad0[1] + bd0) << 16);
        lod.y = f2bf(Dad0[2] + bd0) | ((unsigned)f2bf(Dad0[3] + bd0) << 16);
        lod.z = f2bf(Dmd0[0] + bn0) | ((unsigned)f2bf(Dmd0[1] + bn0) << 16);
        lod.w = f2bf(Dmd0[2] + bn0) | ((unsigned)f2bf(Dmd0[3] + bn0) << 16);
        hid.x = f2bf(Dad1[0] + bd1) | ((unsigned)f2bf(Dad1[1] + bd1) << 16);
        hid.y = f2bf(Dad1[2] + bd1) | ((unsigned)f2bf(Dad1[3] + bd1) << 16);
        hid.z = f2bf(Dmd1[0] + bn1) | ((unsigned)f2bf(Dmd1[1] + bn1) << 16);
        hid.w = f2bf(Dmd1[2] + bn1) | ((unsigned)f2bf(Dmd1[3] + bn1) << 16);
        tab_d[(size_t)node * 32 + l15]      = lod;
        tab_d[(size_t)node * 32 + 16 + l15] = hid;
    }
}

// ---------------------------------------------------------------------------
// Exclusive scan of deg -> rowptr, cursor. (R5-proven, verbatim)
// ---------------------------------------------------------------------------
__global__ __launch_bounds__(1024) void scan_k(
    const int* __restrict__ deg, int* __restrict__ rowptr, int* __restrict__ cursor)
{
    __shared__ int wsum[16];
    __shared__ int carry_s;
    int tid = threadIdx.x;
    int lane = tid & 63, wv = tid >> 6;
    if (tid == 0) carry_s = 0;
    __syncthreads();
    for (int base = 0; base < V_N; base += 1024) {
        int i = base + tid;
        int v = (i < V_N) ? deg[i] : 0;
        int x = v;
        #pragma unroll
        for (int off = 1; off < 64; off <<= 1) {
            int t = __shfl_up(x, off, 64);
            if (lane >= off) x += t;
        }
        if (lane == 63) wsum[wv] = x;
        __syncthreads();
        if (wv == 0 && lane < 16) {
            int s = wsum[lane];
            #pragma unroll
            for (int off = 1; off < 16; off <<= 1) {
                int t = __shfl_up(s, off, 64);
                if (lane >= off) s += t;
            }
            wsum[lane] = s;
        }
        __syncthreads();
        int woff  = (wv == 0) ? 0 : wsum[wv - 1];
        int carry = carry_s;
        int excl  = carry + woff + x - v;
        if (i < V_N) { rowptr[i] = excl; cursor[i] = excl; }
        __syncthreads();
        if (tid == 1023) carry_s = carry + wsum[15];
        __syncthreads();
    }
    if (tid == 0) rowptr[V_N] = carry_s;
}

// ---------------------------------------------------------------------------
// Scatter (R12/R14-proven split): atomics only; pos[e] and csr_src[p].
// ---------------------------------------------------------------------------
__global__ __launch_bounds__(256) void scatter_k(
    const int* __restrict__ dst, const int* __restrict__ src,
    int* __restrict__ cursor, int* __restrict__ pos, int* __restrict__ csr_src)
{
    int i = blockIdx.x * 256 + threadIdx.x;
    if (i < E_N) {
        int p = atomicAdd(&cursor[dst[i]], 1);
        pos[i] = p;
        csr_src[p] = src[i];
    }
}

// ---------------------------------------------------------------------------
// Kernel B: MFMA edge GEMV. (R15-proven, verbatim)
// ---------------------------------------------------------------------------
__global__ __launch_bounds__(256) void edge_gemv_mfma(
    const float* __restrict__ ef, const int* __restrict__ pos,
    const float* __restrict__ Wae, const float* __restrict__ bae,
    const float* __restrict__ Wme, const float* __restrict__ bme,
    unsigned* __restrict__ em)
{
    int tid  = threadIdx.x;
    int lane = tid & 63;
    int l15  = lane & 15, q = lane >> 4;
    bf16x8 B0, B1, B2, B3;
    #pragma unroll
    for (int i = 0; i < 8; ++i) {
        int k = q * 8 + i;
        B0[i] = (short)f2bf(Wae[k * 32 + l15]);
        B1[i] = (short)f2bf(Wae[k * 32 + 16 + l15]);
        B2[i] = (short)f2bf(Wme[k * 32 + l15]);
        B3[i] = (short)f2bf(Wme[k * 32 + 16 + l15]);
    }
    float ba0 = bae[l15], ba1 = bae[16 + l15];
    float bm0 = bme[l15], bm1 = bme[16 + l15];

    int wid = (blockIdx.x * 256 + tid) >> 6;
    int nw  = (gridDim.x * 256) >> 6;
    const int ntiles = E_N / 16;               // 31250 exact
    for (int tile = wid; tile < ntiles; tile += nw) {
        int ebase = tile * 16;
        const float4* ap = (const float4*)(ef + (size_t)(ebase + l15) * 32 + q * 8);
        float4 a0 = ap[0], a1 = ap[1];
        int pv = pos[ebase + l15];
        bf16x8 A;
        A[0] = (short)f2bf(a0.x); A[1] = (short)f2bf(a0.y);
        A[2] = (short)f2bf(a0.z); A[3] = (short)f2bf(a0.w);
        A[4] = (short)f2bf(a1.x); A[5] = (short)f2bf(a1.y);
        A[6] = (short)f2bf(a1.z); A[7] = (short)f2bf(a1.w);
        f32x4 z = {0.f, 0.f, 0.f, 0.f};
        f32x4 D0 = __builtin_amdgcn_mfma_f32_16x16x32_bf16(A, B0, z, 0, 0, 0);
        f32x4 D1 = __builtin_amdgcn_mfma_f32_16x16x32_bf16(A, B1, z, 0, 0, 0);
        f32x4 D2 = __builtin_amdgcn_mfma_f32_16x16x32_bf16(A, B2, z, 0, 0, 0);
        f32x4 D3 = __builtin_amdgcn_mfma_f32_16x16x32_bf16(A, B3, z, 0, 0, 0);
        #pragma unroll
        for (int j = 0; j < 4; ++j) {
            int r = q * 4 + j;
            int p = __shfl(pv, r, 64);
            unsigned lo = f2bf(D0[j] + ba0) | ((unsigned)f2bf(D2[j] + bm0) << 16);
            unsigned hi = f2bf(D1[j] + ba1) | ((unsigned)f2bf(D3[j] + bm1) << 16);
            em[(size_t)p * 32 + l15]      = lo;
            em[(size_t)p * 32 + 16 + l15] = hi;
        }
    }
}

// ---------------------------------------------------------------------------
// Kernel C: per-dst aggregation with DPP group_sum (R13/R14-proven).
// MICRO-CHANGE vs R15: log2e folded into staged Wdot + exp2f (saves 4 v_mul
// per edge; exact up to 1-ulp reassociation).
// ---------------------------------------------------------------------------
__global__ __launch_bounds__(256) void node_gather4(
    const int* __restrict__ rowptr, const int* __restrict__ csr_src,
    const unsigned* __restrict__ em, const uint4* __restrict__ tab_s,
    const uint4* __restrict__ tab_d,
    const float* __restrict__ Wdot,
    const float* __restrict__ Wwn, const float* __restrict__ bwn,
    const float* __restrict__ nf,
    float* __restrict__ out)
{
    __shared__ float ww[1024], wd[32];
    int tid = threadIdx.x;
    for (int i = tid; i < 1024; i += 256) ww[i] = Wwn[i];
    if (tid < 32) wd[tid] = Wdot[tid] * 1.4426950408889634f;   // log2(e)
    __syncthreads();
    int lane = tid & 31;
    int n = blockIdx.x * 8 + (tid >> 5);       // 3750*8 = 30000 exact
    float wdl = wd[lane];

    float da[4], dm[4];
    {
        uint4 v = tab_d[(size_t)n * 32 + lane];
        da[0] = bf_lo(v.x); da[1] = bf_hi(v.x);
        da[2] = bf_lo(v.y); da[3] = bf_hi(v.y);
        dm[0] = bf_lo(v.z); dm[1] = bf_hi(v.z);
        dm[2] = bf_lo(v.w); dm[3] = bf_hi(v.w);
    }

    float acc0 = 0.f, acc1 = 0.f, acc2 = 0.f, acc3 = 0.f;
    float s0 = 0.f, s1 = 0.f, s2 = 0.f, s3 = 0.f;
    int p0 = rowptr[n], p1 = rowptr[n + 1];

    uint4 gc = make_uint4(0, 0, 0, 0);
    unsigned ec = 0;
    if (p0 < p1) {
        int si = csr_src[p0];
        gc = tab_s[(size_t)si * 32 + lane];
        ec = em[(size_t)p0 * 32 + lane];
    }
    for (int p = p0; p < p1; ++p) {
        uint4 g = gc; unsigned ev = ec;
        if (p + 1 < p1) {                      // depth-1 prefetch
            int sn = csr_src[p + 1];
            gc = tab_s[(size_t)sn * 32 + lane];
            ec = em[(size_t)(p + 1) * 32 + lane];
        }
        float ea = bf_lo(ev), me = bf_hi(ev);
        float t0 = lrelu(bf_lo(g.x) + da[0] + ea) * wdl;
        float t1 = lrelu(bf_hi(g.x) + da[1] + ea) * wdl;
        float t2 = lrelu(bf_lo(g.y) + da[2] + ea) * wdl;
        float t3 = lrelu(bf_hi(g.y) + da[3] + ea) * wdl;
        t0 = group_sum(t0, lane);
        t1 = group_sum(t1, lane);
        t2 = group_sum(t2, lane);
        t3 = group_sum(t3, lane);
        float x0 = exp2f(t0), x1 = exp2f(t1);
        float x2 = exp2f(t2), x3 = exp2f(t3);
        float m0 = lrelu(bf_lo(g.z) + dm[0] + me);
        float m1 = lrelu(bf_hi(g.z) + dm[1] + me);
        float m2 = lrelu(bf_lo(g.w) + dm[2] + me);
        float m3 = lrelu(bf_hi(g.w) + dm[3] + me);
        acc0 = fmaf(x0, m0, acc0); s0 += x0;
        acc1 = fmaf(x1, m1, acc1); s1 += x1;
        acc2 = fmaf(x2, m2, acc2); s2 += x2;
        acc3 = fmaf(x3, m3, acc3); s3 += x3;
    }
    // epilogue: Wwn GEMV after acc/s pressure is released
    #pragma unroll
    for (int h = 0; h < 4; ++h) {
        float x = nf[(size_t)n * 128 + h * 32 + lane];
        float a = bwn[lane];
        #pragma unroll
        for (int k = 0; k < 32; ++k)
            a = fmaf(__shfl(x, k, 32), ww[k * 32 + lane], a);
        float accv = (h == 0) ? acc0 : (h == 1) ? acc1 : (h == 2) ? acc2 : acc3;
        float sv   = (h == 0) ? s0   : (h == 1) ? s1   : (h == 2) ? s2   : s3;
        float f = (sv > 0.f) ? accv / sv : 0.f;
        out[(size_t)n * 128 + h * 32 + lane] = lrelu(f + a);
    }
}

extern "C" void kernel_launch(void* const* d_in, const int* in_sizes, int n_in,
                              void* d_out, int out_size, void* d_ws, size_t ws_size,
                              hipStream_t stream)
{
    const float* nf  = (const float*)d_in[0];
    const float* ef  = (const float*)d_in[1];
    const int*   src = (const int*)d_in[2];
    const int*   dst = (const int*)d_in[3];
    const float* Was = (const float*)d_in[4],  *bas = (const float*)d_in[5];
    const float* Wad = (const float*)d_in[6],  *bad = (const float*)d_in[7];
    const float* Wae = (const float*)d_in[8],  *bae = (const float*)d_in[9];
    const float* Wdot= (const float*)d_in[10];
    const float* Wms = (const float*)d_in[12], *bms = (const float*)d_in[13];
    const float* Wmd = (const float*)d_in[14], *bmd = (const float*)d_in[15];
    const float* Wme = (const float*)d_in[16], *bme = (const float*)d_in[17];
    const float* Wwn = (const float*)d_in[18], *bwn = (const float*)d_in[19];

    // ws layout (~99.1 MB): em (64) | tab_s (15.36) | tab_d (15.36) | ints
    const size_t em_w  = (size_t)E_N * 32;             // u32 words
    const size_t tab_w = (size_t)V_N * 32;             // uint4 elems
    unsigned* em     = (unsigned*)d_ws;
    uint4*    tab_s  = (uint4*)(em + em_w);
    uint4*    tab_d  = tab_s + tab_w;
    int*      deg    = (int*)(tab_d + tab_w);          // V
    int*      rowptr = deg + V_N;                      // V+1
    int*      cursor = rowptr + V_N + 1;               // V
    int*      pos    = cursor + V_N;                   // E
    int*      csr_src= pos + E_N;                      // E

    hipMemsetAsync(deg, 0, V_N * sizeof(int), stream);

    const int ebk = (E_N + 255) / 256;                 // 1954 blocks

    xform_hist_mfma<<<XW + HB, 256, 0, stream>>>(nf, Was, bas, Wms, bms,
                                                 Wad, bad, Wmd, bmd, dst,
                                                 tab_s, tab_d, deg);
    scan_k<<<1, 1024, 0, stream>>>(deg, rowptr, cursor);
    scatter_k<<<ebk, 256, 0, stream>>>(dst, src, cursor, pos, csr_src);
    edge_gemv_mfma<<<2048, 256, 0, stream>>>(ef, pos, Wae, bae, Wme, bme, em);
    node_gather4<<<3750, 256, 0, stream>>>(rowptr, csr_src, em, tab_s, tab_d,
                                           Wdot, Wwn, bwn, nf, (float*)d_out);
}